// Round 1
// baseline (1418.846 us; speedup 1.0000x reference)
//
#include <hip/hip_runtime.h>

#define Nn 16384
#define Dm 256
#define Ff 1024

typedef __attribute__((ext_vector_type(8))) short bf16x8;
typedef __attribute__((ext_vector_type(4))) float f32x4;

__device__ __forceinline__ unsigned short f2bf(float f) {
  union { float f; unsigned u; } v; v.f = f;
  return (unsigned short)((v.u + 0x7FFFu + ((v.u >> 16) & 1u)) >> 16);
}

// ---------------- weight convert + transpose: wt[b][j][k] = bf16(w[b][k][j]) ----------------
__global__ void wconv_kernel(const float* __restrict__ w, unsigned short* __restrict__ wt,
                             int B, int K, int J) {
  size_t total = (size_t)B * K * J;
  size_t kj = (size_t)K * J;
  for (size_t i = (size_t)blockIdx.x * blockDim.x + threadIdx.x; i < total;
       i += (size_t)gridDim.x * blockDim.x) {
    int b = (int)(i / kj);
    int rem = (int)(i - (size_t)b * kj);
    int k = rem / J, j = rem - k * J;
    wt[(size_t)b * kj + (size_t)j * K + k] = f2bf(w[i]);
  }
}

// ---------------- CSR build ----------------
__global__ void count_kernel(const int* __restrict__ dst, int E, int* __restrict__ cnt) {
  for (int e = blockIdx.x * blockDim.x + threadIdx.x; e < E; e += gridDim.x * blockDim.x)
    atomicAdd(&cnt[dst[e]], 1);
}

__global__ void scan_kernel(const int* __restrict__ cnt, int* __restrict__ rowptr,
                            int* __restrict__ cursor, int n) {
  __shared__ int sd[256];
  __shared__ int stot;
  int tid = threadIdx.x;
  int run = 0;
  for (int base = 0; base < n; base += 256) {
    int v = cnt[base + tid];
    sd[tid] = v;
    __syncthreads();
    for (int offt = 1; offt < 256; offt <<= 1) {
      int tval = (tid >= offt) ? sd[tid - offt] : 0;
      __syncthreads();
      sd[tid] += tval;
      __syncthreads();
    }
    int ex = sd[tid] - v;  // exclusive
    rowptr[base + tid] = run + ex;
    cursor[base + tid] = run + ex;
    if (tid == 255) stot = sd[255];
    __syncthreads();
    run += stot;
  }
  if (tid == 0) rowptr[n] = run;
}

__global__ void fill_kernel(const int* __restrict__ src, const int* __restrict__ dst, int E,
                            int* __restrict__ cursor, int* __restrict__ csrc) {
  for (int e = blockIdx.x * blockDim.x + threadIdx.x; e < E; e += gridDim.x * blockDim.x) {
    int pos = atomicAdd(&cursor[dst[e]], 1);
    csrc[pos] = src[e];
  }
}

// ---------------- per-layer input prep ----------------
__global__ void prep_kernel(const float* __restrict__ hf, const float* __restrict__ hs,
                            float* __restrict__ x0f, unsigned short* __restrict__ x0b,
                            float* __restrict__ x1f, unsigned short* __restrict__ x1b, int total) {
  for (int i = blockIdx.x * blockDim.x + threadIdx.x; i < total; i += gridDim.x * blockDim.x) {
    float a = hf[i], b = hs[i];
    float s = a + b;
    x0f[i] = s; x0b[i] = f2bf(s);
    x1f[i] = b; x1b[i] = f2bf(b);
  }
}

// ---------------- bf16 MFMA GEMM: C[M][Ncol] = A[M][K] * Bt[Ncol][K]^T ----------------
// EPI 0: store f32. EPI 1: +bias, relu, store bf16. EPI 2: +bias +resid, store f32.
template <int EPI>
__global__ __launch_bounds__(256, 2) void gemm_kernel(
    const unsigned short* __restrict__ A, const unsigned short* __restrict__ Bt,
    float* __restrict__ outF, unsigned short* __restrict__ outB,
    const float* __restrict__ bias, const float* __restrict__ resid,
    int M, int K, int Ncol) {
  __shared__ __align__(16) unsigned short sA[128 * 32];
  __shared__ __align__(16) unsigned short sB[128 * 32];
  int tid = threadIdx.x;
  int wave = tid >> 6, lane = tid & 63;
  int l16 = lane & 15, lhi = lane >> 4;
  int brow = blockIdx.x, bcol = blockIdx.y;
  int wm = wave >> 1, wn = wave & 1;  // 2x2 waves, wave tile 64x64

  const unsigned short* Ab = A + (size_t)brow * 128 * K;
  const unsigned short* Bb = Bt + (size_t)bcol * 128 * K;

  f32x4 acc[4][4] = {};

  for (int k0 = 0; k0 < K; k0 += 32) {
#pragma unroll
    for (int q = 0; q < 2; ++q) {
      int e = (q * 256 + tid) * 8;
      int r = e >> 5, kk = e & 31;
      *(int4*)&sA[e] = *(const int4*)&Ab[(size_t)r * K + k0 + kk];
      *(int4*)&sB[e] = *(const int4*)&Bb[(size_t)r * K + k0 + kk];
    }
    __syncthreads();
    bf16x8 af[4], bfr[4];
#pragma unroll
    for (int mi = 0; mi < 4; ++mi)
      af[mi] = *(const bf16x8*)&sA[(wm * 64 + mi * 16 + l16) * 32 + lhi * 8];
#pragma unroll
    for (int ni = 0; ni < 4; ++ni)
      bfr[ni] = *(const bf16x8*)&sB[(wn * 64 + ni * 16 + l16) * 32 + lhi * 8];
#pragma unroll
    for (int mi = 0; mi < 4; ++mi)
#pragma unroll
      for (int ni = 0; ni < 4; ++ni)
        acc[mi][ni] = __builtin_amdgcn_mfma_f32_16x16x32_bf16(af[mi], bfr[ni], acc[mi][ni], 0, 0, 0);
    __syncthreads();
  }

#pragma unroll
  for (int mi = 0; mi < 4; ++mi) {
#pragma unroll
    for (int ni = 0; ni < 4; ++ni) {
#pragma unroll
      for (int j = 0; j < 4; ++j) {
        int r = brow * 128 + wm * 64 + mi * 16 + lhi * 4 + j;
        int c = bcol * 128 + wn * 64 + ni * 16 + l16;
        float v = acc[mi][ni][j];
        if (EPI == 0) {
          outF[(size_t)r * Ncol + c] = v;
        } else if (EPI == 1) {
          v += bias[c];
          v = v > 0.f ? v : 0.f;
          outB[(size_t)r * Ncol + c] = f2bf(v);
        } else {
          v += bias[c] + resid[(size_t)r * Ncol + c];
          outF[(size_t)r * Ncol + c] = v;
        }
      }
    }
  }
}

// ---------------- attention scores: a_s[n][h] = sum_c h[n][h*64+c]*asr[h*64+c] ----------------
__global__ __launch_bounds__(256) void score_kernel(const float* __restrict__ h,
                                                    const float* __restrict__ asr,
                                                    const float* __restrict__ ads,
                                                    float* __restrict__ a_s,
                                                    float* __restrict__ a_d) {
  int n = blockIdx.x, tid = threadIdx.x;
  int head = tid >> 6, lane = tid & 63;
  float hv = h[(size_t)n * 256 + tid];
  float s1 = hv * asr[tid];
  float s2 = hv * ads[tid];
#pragma unroll
  for (int off = 32; off; off >>= 1) {
    s1 += __shfl_xor(s1, off);
    s2 += __shfl_xor(s2, off);
  }
  if (lane == 0) {
    a_s[n * 4 + head] = s1;
    a_d[n * 4 + head] = s2;
  }
}

// ---------------- fused segment softmax + aggregation + bias + residual + LN1 ----------------
__global__ __launch_bounds__(256) void agg_kernel(
    const float* __restrict__ h, const float* __restrict__ a_s, const float* __restrict__ a_d,
    const int* __restrict__ rowptr, const int* __restrict__ csrc,
    const float* __restrict__ bias, const float* __restrict__ xres,
    const float* __restrict__ g1, const float* __restrict__ bt1,
    float* __restrict__ x1f, unsigned short* __restrict__ x1b) {
  __shared__ float se[256 * 4];
  __shared__ int ss[256];
  __shared__ float smax[4];
  __shared__ float red[8];
  int n = blockIdx.x, tid = threadIdx.x;
  int head = tid >> 6, lane = tid & 63;
  int beg = rowptr[n], end = rowptr[n + 1];
  float4 adv = *(const float4*)&a_d[n * 4];
  float acc = 0.f, den = 0.f, m = -__builtin_inff();

  for (int base = beg; base < end; base += 256) {
    int cnt = min(256, end - base);
    if (tid < cnt) {
      int s = csrc[base + tid];
      ss[tid] = s;
      float4 asv = *(const float4*)&a_s[s * 4];
      float e0 = asv.x + adv.x; e0 = e0 > 0.f ? e0 : 0.2f * e0;
      float e1 = asv.y + adv.y; e1 = e1 > 0.f ? e1 : 0.2f * e1;
      float e2 = asv.z + adv.z; e2 = e2 > 0.f ? e2 : 0.2f * e2;
      float e3 = asv.w + adv.w; e3 = e3 > 0.f ? e3 : 0.2f * e3;
      se[tid * 4 + 0] = e0; se[tid * 4 + 1] = e1;
      se[tid * 4 + 2] = e2; se[tid * 4 + 3] = e3;
    } else {
      se[tid * 4 + 0] = -__builtin_inff(); se[tid * 4 + 1] = -__builtin_inff();
      se[tid * 4 + 2] = -__builtin_inff(); se[tid * 4 + 3] = -__builtin_inff();
    }
    __syncthreads();
    // wave w reduces chunk max for head w over all 256 slots
    float v = fmaxf(fmaxf(se[lane * 4 + head], se[(lane + 64) * 4 + head]),
                    fmaxf(se[(lane + 128) * 4 + head], se[(lane + 192) * 4 + head]));
#pragma unroll
    for (int off = 32; off; off >>= 1) v = fmaxf(v, __shfl_xor(v, off));
    float mn = fmaxf(m, v);
    float r = __expf(m - mn);  // m=-inf on first chunk -> r=0; mn finite (cnt>=1)
    acc *= r; den *= r; m = mn;
    if (lane == 0) smax[head] = mn;
    __syncthreads();
    if (tid < cnt) {
      se[tid * 4 + 0] = __expf(se[tid * 4 + 0] - smax[0]);
      se[tid * 4 + 1] = __expf(se[tid * 4 + 1] - smax[1]);
      se[tid * 4 + 2] = __expf(se[tid * 4 + 2] - smax[2]);
      se[tid * 4 + 3] = __expf(se[tid * 4 + 3] - smax[3]);
    }
    __syncthreads();
    for (int i = 0; i < cnt; ++i) {
      float w = se[i * 4 + head];  // LDS broadcast within wave
      acc = fmaf(h[(size_t)ss[i] * 256 + tid], w, acc);
      den += w;
    }
    __syncthreads();
  }

  float outv = acc / fmaxf(den, 1e-16f) + bias[tid] + xres[(size_t)n * 256 + tid];
  // LayerNorm over 256 channels
  float s1 = outv, s2 = outv * outv;
#pragma unroll
  for (int off = 32; off; off >>= 1) {
    s1 += __shfl_xor(s1, off);
    s2 += __shfl_xor(s2, off);
  }
  if (lane == 0) { red[head] = s1; red[4 + head] = s2; }
  __syncthreads();
  s1 = red[0] + red[1] + red[2] + red[3];
  s2 = red[4] + red[5] + red[6] + red[7];
  float mean = s1 * (1.f / 256.f);
  float var = s2 * (1.f / 256.f) - mean * mean;
  float y = (outv - mean) * rsqrtf(var + 1e-5f) * g1[tid] + bt1[tid];
  x1f[(size_t)n * 256 + tid] = y;
  x1b[(size_t)n * 256 + tid] = f2bf(y);
}

// ---------------- LayerNorm (t -> out) ----------------
__global__ __launch_bounds__(256) void ln_kernel(const float* __restrict__ t,
                                                 const float* __restrict__ g,
                                                 const float* __restrict__ b,
                                                 float* __restrict__ out) {
  __shared__ float red[8];
  int n = blockIdx.x, tid = threadIdx.x;
  int head = tid >> 6, lane = tid & 63;
  float v = t[(size_t)n * 256 + tid];
  float s1 = v, s2 = v * v;
#pragma unroll
  for (int off = 32; off; off >>= 1) {
    s1 += __shfl_xor(s1, off);
    s2 += __shfl_xor(s2, off);
  }
  if (lane == 0) { red[head] = s1; red[4 + head] = s2; }
  __syncthreads();
  s1 = red[0] + red[1] + red[2] + red[3];
  s2 = red[4] + red[5] + red[6] + red[7];
  float mean = s1 * (1.f / 256.f);
  float var = s2 * (1.f / 256.f) - mean * mean;
  out[(size_t)n * 256 + tid] = (v - mean) * rsqrtf(var + 1e-5f) * g[tid] + b[tid];
}

extern "C" void kernel_launch(void* const* d_in, const int* in_sizes, int n_in,
                              void* d_out, int out_size, void* d_ws, size_t ws_size,
                              hipStream_t stream) {
  const float* hf_in = (const float*)d_in[0];
  const float* hs_in = (const float*)d_in[1];
  const int* ei = (const int*)d_in[2];
  const int E = in_sizes[2] / 2;
  const float* Wgat = (const float*)d_in[3];
  const float* att_src = (const float*)d_in[4];
  const float* att_dst = (const float*)d_in[5];
  const float* bias_gat = (const float*)d_in[6];
  const float* W1 = (const float*)d_in[7];
  const float* b1 = (const float*)d_in[8];
  const float* W2 = (const float*)d_in[9];
  const float* b2 = (const float*)d_in[10];
  const float* g1 = (const float*)d_in[11];
  const float* bt1 = (const float*)d_in[12];
  const float* g2 = (const float*)d_in[13];
  const float* bt2 = (const float*)d_in[14];
  const int* src = ei;
  const int* dst = ei + E;

  // ---- carve workspace ----
  char* wsp = (char*)d_ws;
  size_t off = 0;
  auto carve = [&](size_t bytes) -> void* {
    void* p = wsp + off;
    off += (bytes + 255) & ~(size_t)255;
    return p;
  };
  unsigned short* Wgt  = (unsigned short*)carve((size_t)8 * 256 * 256 * 2);
  unsigned short* W1t  = (unsigned short*)carve((size_t)8 * 256 * 1024 * 2);
  unsigned short* W2t  = (unsigned short*)carve((size_t)8 * 1024 * 256 * 2);
  int* cnt      = (int*)carve((size_t)Nn * 4);
  int* rowptr   = (int*)carve((size_t)(Nn + 1) * 4);
  int* cursor   = (int*)carve((size_t)Nn * 4);
  int* csrc     = (int*)carve((size_t)E * 4);
  float* x0f    = (float*)carve((size_t)Nn * Dm * 4);
  float* x1inf  = (float*)carve((size_t)Nn * Dm * 4);
  unsigned short* x0b   = (unsigned short*)carve((size_t)Nn * Dm * 2);
  unsigned short* x1inb = (unsigned short*)carve((size_t)Nn * Dm * 2);
  float* h      = (float*)carve((size_t)Nn * Dm * 4);  // also reused as FFN output t
  float* a_s    = (float*)carve((size_t)Nn * 4 * 4);
  float* a_d    = (float*)carve((size_t)Nn * 4 * 4);
  float* x1f    = (float*)carve((size_t)Nn * Dm * 4);
  unsigned short* x1b = (unsigned short*)carve((size_t)Nn * Dm * 2);
  unsigned short* f_b = (unsigned short*)carve((size_t)Nn * Ff * 2);
  if (off > ws_size) return;  // workspace too small — fail visibly

  // ---- once per call: weights + CSR ----
  wconv_kernel<<<1024, 256, 0, stream>>>(Wgat, Wgt, 8, 256, 256);
  wconv_kernel<<<1024, 256, 0, stream>>>(W1, W1t, 8, 256, 1024);
  wconv_kernel<<<1024, 256, 0, stream>>>(W2, W2t, 8, 1024, 256);
  hipMemsetAsync(cnt, 0, (size_t)Nn * 4, stream);
  count_kernel<<<1024, 256, 0, stream>>>(dst, E, cnt);
  scan_kernel<<<1, 256, 0, stream>>>(cnt, rowptr, cursor, Nn);
  fill_kernel<<<1024, 256, 0, stream>>>(src, dst, E, cursor, csrc);

  float* out_hf = (float*)d_out;
  float* out_hs = out_hf + (size_t)Nn * Dm;

  for (int l = 0; l < 4; ++l) {
    const float* hf_s = l ? (const float*)out_hf : hf_in;
    const float* hs_s = l ? (const float*)out_hs : hs_in;
    prep_kernel<<<2048, 256, 0, stream>>>(hf_s, hs_s, x0f, x0b, x1inf, x1inb, Nn * Dm);
    for (int s = 0; s < 2; ++s) {
      int b = s * 4 + l;
      const unsigned short* xb = s ? x1inb : x0b;
      const float* xf = s ? x1inf : x0f;
      // h = xin @ Wg
      gemm_kernel<0><<<dim3(128, 2), 256, 0, stream>>>(
          xb, Wgt + (size_t)b * 256 * 256, h, nullptr, nullptr, nullptr, Nn, 256, 256);
      // attention scores
      score_kernel<<<Nn, 256, 0, stream>>>(h, att_src + (size_t)b * 256,
                                           att_dst + (size_t)b * 256, a_s, a_d);
      // segment softmax + aggregate + bias + residual + LN1 -> x1
      agg_kernel<<<Nn, 256, 0, stream>>>(h, a_s, a_d, rowptr, csrc,
                                         bias_gat + (size_t)b * 256, xf,
                                         g1 + (size_t)b * 256, bt1 + (size_t)b * 256,
                                         x1f, x1b);
      // f = relu(x1 @ W1 + b1)  (bf16 out)
      gemm_kernel<1><<<dim3(128, 8), 256, 0, stream>>>(
          x1b, W1t + (size_t)b * 256 * 1024, nullptr, f_b,
          b1 + (size_t)b * 1024, nullptr, Nn, 256, 1024);
      // t = f @ W2 + b2 + x1   (reuse h buffer as t)
      gemm_kernel<2><<<dim3(128, 2), 256, 0, stream>>>(
          f_b, W2t + (size_t)b * 1024 * 256, h, nullptr,
          b2 + (size_t)b * 256, x1f, Nn, 1024, 256);
      // LN2 -> state
      ln_kernel<<<Nn, 256, 0, stream>>>(h, g2 + (size_t)b * 256, bt2 + (size_t)b * 256,
                                        s ? out_hs : out_hf);
    }
  }
}

// Round 2
// 1224.411 us; speedup vs baseline: 1.1588x; 1.1588x over previous
//
#include <hip/hip_runtime.h>

#define Nn 16384
#define Dm 256
#define Ff 1024

typedef __attribute__((ext_vector_type(8))) short bf16x8;
typedef __attribute__((ext_vector_type(4))) float f32x4;

typedef const __attribute__((address_space(1))) unsigned int glb_u32;
typedef __attribute__((address_space(3))) unsigned int lds_u32;

__device__ __forceinline__ void async_copy16(const void* g, void* l) {
  __builtin_amdgcn_global_load_lds((glb_u32*)g, (lds_u32*)l, 16, 0, 0);
}

__device__ __forceinline__ unsigned short f2bf(float f) {
  union { float f; unsigned u; } v; v.f = f;
  return (unsigned short)((v.u + 0x7FFFu + ((v.u >> 16) & 1u)) >> 16);
}

__device__ __forceinline__ float bf2f(unsigned short u) {
  union { unsigned u; float f; } v; v.u = ((unsigned)u) << 16;
  return v.f;
}

// ---------------- weight convert + transpose: wt[b][j][k] = bf16(w[b][k][j]) ----------------
__global__ void wconv_kernel(const float* __restrict__ w, unsigned short* __restrict__ wt,
                             int B, int K, int J) {
  size_t total = (size_t)B * K * J;
  size_t kj = (size_t)K * J;
  for (size_t i = (size_t)blockIdx.x * blockDim.x + threadIdx.x; i < total;
       i += (size_t)gridDim.x * blockDim.x) {
    int b = (int)(i / kj);
    int rem = (int)(i - (size_t)b * kj);
    int k = rem / J, j = rem - k * J;
    wt[(size_t)b * kj + (size_t)j * K + k] = f2bf(w[i]);
  }
}

// ---------------- CSR build ----------------
__global__ void count_kernel(const int* __restrict__ dst, int E, int* __restrict__ cnt) {
  for (int e = blockIdx.x * blockDim.x + threadIdx.x; e < E; e += gridDim.x * blockDim.x)
    atomicAdd(&cnt[dst[e]], 1);
}

__global__ void scan_kernel(const int* __restrict__ cnt, int* __restrict__ rowptr,
                            int* __restrict__ cursor, int n) {
  __shared__ int sd[256];
  __shared__ int stot;
  int tid = threadIdx.x;
  int run = 0;
  for (int base = 0; base < n; base += 256) {
    int v = cnt[base + tid];
    sd[tid] = v;
    __syncthreads();
    for (int offt = 1; offt < 256; offt <<= 1) {
      int tval = (tid >= offt) ? sd[tid - offt] : 0;
      __syncthreads();
      sd[tid] += tval;
      __syncthreads();
    }
    int ex = sd[tid] - v;  // exclusive
    rowptr[base + tid] = run + ex;
    cursor[base + tid] = run + ex;
    if (tid == 255) stot = sd[255];
    __syncthreads();
    run += stot;
  }
  if (tid == 0) rowptr[n] = run;
}

__global__ void fill_kernel(const int* __restrict__ src, const int* __restrict__ dst, int E,
                            int* __restrict__ cursor, int* __restrict__ csrc) {
  for (int e = blockIdx.x * blockDim.x + threadIdx.x; e < E; e += gridDim.x * blockDim.x) {
    int pos = atomicAdd(&cursor[dst[e]], 1);
    csrc[pos] = src[e];
  }
}

// ---------------- per-layer input prep ----------------
__global__ void prep_kernel(const float* __restrict__ hf, const float* __restrict__ hs,
                            float* __restrict__ x0f, unsigned short* __restrict__ x0b,
                            float* __restrict__ x1f, unsigned short* __restrict__ x1b, int total) {
  for (int i = blockIdx.x * blockDim.x + threadIdx.x; i < total; i += gridDim.x * blockDim.x) {
    float a = hf[i], b = hs[i];
    float s = a + b;
    x0f[i] = s; x0b[i] = f2bf(s);
    x1f[i] = b; x1b[i] = f2bf(b);
  }
}

// ---------------- bf16 MFMA GEMM: C[M][Ncol] = A[M][K] * Bt[Ncol][K]^T ----------------
// EPI 1: +bias, relu, store bf16. EPI 2: +bias +resid, store f32. EPI 3: plain store bf16.
template <int EPI>
__global__ __launch_bounds__(256, 2) void gemm_kernel(
    const unsigned short* __restrict__ A, const unsigned short* __restrict__ Bt,
    float* __restrict__ outF, unsigned short* __restrict__ outB,
    const float* __restrict__ bias, const float* __restrict__ resid,
    int M, int K, int Ncol) {
  __shared__ __align__(16) unsigned short sA[128 * 32];
  __shared__ __align__(16) unsigned short sB[128 * 32];
  int tid = threadIdx.x;
  int wave = tid >> 6, lane = tid & 63;
  int l16 = lane & 15, lhi = lane >> 4;
  int brow = blockIdx.x, bcol = blockIdx.y;
  int wm = wave >> 1, wn = wave & 1;  // 2x2 waves, wave tile 64x64

  const unsigned short* Ab = A + (size_t)brow * 128 * K;
  const unsigned short* Bb = Bt + (size_t)bcol * 128 * K;

  // staging: per wave-issue, 16 rows x 64B; lane l -> row +l/4, bytes (l&3)*16
  int ldrow = lane >> 2;
  int ldk = (lane & 3) * 8;

  f32x4 acc[4][4] = {};

  for (int k0 = 0; k0 < K; k0 += 32) {
#pragma unroll
    for (int q = 0; q < 2; ++q) {
      int r0 = wave * 16 + q * 64;
      async_copy16(Ab + (size_t)(r0 + ldrow) * K + k0 + ldk, &sA[r0 * 32]);
      async_copy16(Bb + (size_t)(r0 + ldrow) * K + k0 + ldk, &sB[r0 * 32]);
    }
    __syncthreads();
    bf16x8 af[4], bfr[4];
#pragma unroll
    for (int mi = 0; mi < 4; ++mi)
      af[mi] = *(const bf16x8*)&sA[(wm * 64 + mi * 16 + l16) * 32 + lhi * 8];
#pragma unroll
    for (int ni = 0; ni < 4; ++ni)
      bfr[ni] = *(const bf16x8*)&sB[(wn * 64 + ni * 16 + l16) * 32 + lhi * 8];
#pragma unroll
    for (int mi = 0; mi < 4; ++mi)
#pragma unroll
      for (int ni = 0; ni < 4; ++ni)
        acc[mi][ni] = __builtin_amdgcn_mfma_f32_16x16x32_bf16(af[mi], bfr[ni], acc[mi][ni], 0, 0, 0);
    __syncthreads();
  }

#pragma unroll
  for (int mi = 0; mi < 4; ++mi) {
#pragma unroll
    for (int ni = 0; ni < 4; ++ni) {
#pragma unroll
      for (int j = 0; j < 4; ++j) {
        int r = brow * 128 + wm * 64 + mi * 16 + lhi * 4 + j;
        int c = bcol * 128 + wn * 64 + ni * 16 + l16;
        float v = acc[mi][ni][j];
        if (EPI == 1) {
          v += bias[c];
          v = v > 0.f ? v : 0.f;
          outB[(size_t)r * Ncol + c] = f2bf(v);
        } else if (EPI == 2) {
          v += bias[c] + resid[(size_t)r * Ncol + c];
          outF[(size_t)r * Ncol + c] = v;
        } else {
          outB[(size_t)r * Ncol + c] = f2bf(v);
        }
      }
    }
  }
}

// ---------------- attention scores from bf16 h ----------------
__global__ __launch_bounds__(256) void score_kernel(const unsigned short* __restrict__ hb,
                                                    const float* __restrict__ asr,
                                                    const float* __restrict__ ads,
                                                    float* __restrict__ a_s,
                                                    float* __restrict__ a_d) {
  int n = blockIdx.x, tid = threadIdx.x;
  int head = tid >> 6, lane = tid & 63;
  float hv = bf2f(hb[(size_t)n * 256 + tid]);
  float s1 = hv * asr[tid];
  float s2 = hv * ads[tid];
#pragma unroll
  for (int off = 32; off; off >>= 1) {
    s1 += __shfl_xor(s1, off);
    s2 += __shfl_xor(s2, off);
  }
  if (lane == 0) {
    a_s[n * 4 + head] = s1;
    a_d[n * 4 + head] = s2;
  }
}

// ---------------- fused segment softmax + aggregation + bias + residual + LN1 ----------------
__global__ __launch_bounds__(256) void agg_kernel(
    const unsigned short* __restrict__ hb, const float* __restrict__ a_s,
    const float* __restrict__ a_d,
    const int* __restrict__ rowptr, const int* __restrict__ csrc,
    const float* __restrict__ bias, const float* __restrict__ xres,
    const float* __restrict__ g1, const float* __restrict__ bt1,
    float* __restrict__ x1f, unsigned short* __restrict__ x1b) {
  __shared__ float se[4][256];  // [head][slot] — lane-consecutive or broadcast access only
  __shared__ int ss[256];
  __shared__ float smax[4];
  __shared__ float red[8];
  int n = blockIdx.x, tid = threadIdx.x;
  int head = tid >> 6, lane = tid & 63;
  int beg = rowptr[n], end = rowptr[n + 1];
  float4 adv = *(const float4*)&a_d[n * 4];
  float acc = 0.f, den = 0.f, m = -__builtin_inff();

  for (int base = beg; base < end; base += 256) {
    int cnt = min(256, end - base);
    if (tid < cnt) {
      int s = csrc[base + tid];
      ss[tid] = s;
      float4 asv = *(const float4*)&a_s[s * 4];
      float e0 = asv.x + adv.x; e0 = e0 > 0.f ? e0 : 0.2f * e0;
      float e1 = asv.y + adv.y; e1 = e1 > 0.f ? e1 : 0.2f * e1;
      float e2 = asv.z + adv.z; e2 = e2 > 0.f ? e2 : 0.2f * e2;
      float e3 = asv.w + adv.w; e3 = e3 > 0.f ? e3 : 0.2f * e3;
      se[0][tid] = e0; se[1][tid] = e1; se[2][tid] = e2; se[3][tid] = e3;
    } else {
      se[0][tid] = -__builtin_inff(); se[1][tid] = -__builtin_inff();
      se[2][tid] = -__builtin_inff(); se[3][tid] = -__builtin_inff();
    }
    __syncthreads();
    // wave `head` reduces chunk max for its head over all 256 slots (lane-consecutive reads)
    float v = fmaxf(fmaxf(se[head][lane], se[head][lane + 64]),
                    fmaxf(se[head][lane + 128], se[head][lane + 192]));
#pragma unroll
    for (int off = 32; off; off >>= 1) v = fmaxf(v, __shfl_xor(v, off));
    float mn = fmaxf(m, v);
    float r = __expf(m - mn);  // m=-inf on first chunk -> r=0; mn finite (cnt>=1)
    acc *= r; den *= r; m = mn;
    if (lane == 0) smax[head] = mn;
    __syncthreads();
    if (tid < cnt) {
      se[0][tid] = __expf(se[0][tid] - smax[0]);
      se[1][tid] = __expf(se[1][tid] - smax[1]);
      se[2][tid] = __expf(se[2][tid] - smax[2]);
      se[3][tid] = __expf(se[3][tid] - smax[3]);
    }
    __syncthreads();
    for (int i = 0; i < cnt; ++i) {
      float w = se[head][i];  // broadcast within wave
      acc = fmaf(bf2f(hb[(size_t)ss[i] * 256 + tid]), w, acc);
      den += w;
    }
    __syncthreads();
  }

  float outv = acc / fmaxf(den, 1e-16f) + bias[tid] + xres[(size_t)n * 256 + tid];
  // LayerNorm over 256 channels
  float s1 = outv, s2 = outv * outv;
#pragma unroll
  for (int off = 32; off; off >>= 1) {
    s1 += __shfl_xor(s1, off);
    s2 += __shfl_xor(s2, off);
  }
  if (lane == 0) { red[head] = s1; red[4 + head] = s2; }
  __syncthreads();
  s1 = red[0] + red[1] + red[2] + red[3];
  s2 = red[4] + red[5] + red[6] + red[7];
  float mean = s1 * (1.f / 256.f);
  float var = s2 * (1.f / 256.f) - mean * mean;
  float y = (outv - mean) * rsqrtf(var + 1e-5f) * g1[tid] + bt1[tid];
  x1f[(size_t)n * 256 + tid] = y;
  x1b[(size_t)n * 256 + tid] = f2bf(y);
}

// ---------------- LayerNorm (t -> out) ----------------
__global__ __launch_bounds__(256) void ln_kernel(const float* __restrict__ t,
                                                 const float* __restrict__ g,
                                                 const float* __restrict__ b,
                                                 float* __restrict__ out) {
  __shared__ float red[8];
  int n = blockIdx.x, tid = threadIdx.x;
  int head = tid >> 6, lane = tid & 63;
  float v = t[(size_t)n * 256 + tid];
  float s1 = v, s2 = v * v;
#pragma unroll
  for (int off = 32; off; off >>= 1) {
    s1 += __shfl_xor(s1, off);
    s2 += __shfl_xor(s2, off);
  }
  if (lane == 0) { red[head] = s1; red[4 + head] = s2; }
  __syncthreads();
  s1 = red[0] + red[1] + red[2] + red[3];
  s2 = red[4] + red[5] + red[6] + red[7];
  float mean = s1 * (1.f / 256.f);
  float var = s2 * (1.f / 256.f) - mean * mean;
  out[(size_t)n * 256 + tid] = (v - mean) * rsqrtf(var + 1e-5f) * g[tid] + b[tid];
}

extern "C" void kernel_launch(void* const* d_in, const int* in_sizes, int n_in,
                              void* d_out, int out_size, void* d_ws, size_t ws_size,
                              hipStream_t stream) {
  const float* hf_in = (const float*)d_in[0];
  const float* hs_in = (const float*)d_in[1];
  const int* ei = (const int*)d_in[2];
  const int E = in_sizes[2] / 2;
  const float* Wgat = (const float*)d_in[3];
  const float* att_src = (const float*)d_in[4];
  const float* att_dst = (const float*)d_in[5];
  const float* bias_gat = (const float*)d_in[6];
  const float* W1 = (const float*)d_in[7];
  const float* b1 = (const float*)d_in[8];
  const float* W2 = (const float*)d_in[9];
  const float* b2 = (const float*)d_in[10];
  const float* g1 = (const float*)d_in[11];
  const float* bt1 = (const float*)d_in[12];
  const float* g2 = (const float*)d_in[13];
  const float* bt2 = (const float*)d_in[14];
  const int* src = ei;
  const int* dst = ei + E;

  // ---- carve workspace ----
  char* wsp = (char*)d_ws;
  size_t off = 0;
  auto carve = [&](size_t bytes) -> void* {
    void* p = wsp + off;
    off += (bytes + 255) & ~(size_t)255;
    return p;
  };
  unsigned short* Wgt  = (unsigned short*)carve((size_t)8 * 256 * 256 * 2);
  unsigned short* W1t  = (unsigned short*)carve((size_t)8 * 256 * 1024 * 2);
  unsigned short* W2t  = (unsigned short*)carve((size_t)8 * 1024 * 256 * 2);
  int* cnt      = (int*)carve((size_t)Nn * 4);
  int* rowptr   = (int*)carve((size_t)(Nn + 1) * 4);
  int* cursor   = (int*)carve((size_t)Nn * 4);
  int* csrc     = (int*)carve((size_t)E * 4);
  float* x0f    = (float*)carve((size_t)Nn * Dm * 4);
  float* x1inf  = (float*)carve((size_t)Nn * Dm * 4);
  unsigned short* x0b   = (unsigned short*)carve((size_t)Nn * Dm * 2);
  unsigned short* x1inb = (unsigned short*)carve((size_t)Nn * Dm * 2);
  unsigned short* hbuf  = (unsigned short*)carve((size_t)Nn * Dm * 2);  // proj output bf16
  float* tf     = (float*)carve((size_t)Nn * Dm * 4);                   // FFN output (pre-LN2)
  float* a_s    = (float*)carve((size_t)Nn * 4 * 4);
  float* a_d    = (float*)carve((size_t)Nn * 4 * 4);
  float* x1f    = (float*)carve((size_t)Nn * Dm * 4);
  unsigned short* x1b = (unsigned short*)carve((size_t)Nn * Dm * 2);
  unsigned short* f_b = (unsigned short*)carve((size_t)Nn * Ff * 2);
  if (off > ws_size) return;  // workspace too small — fail visibly

  // ---- once per call: weights + CSR ----
  wconv_kernel<<<1024, 256, 0, stream>>>(Wgat, Wgt, 8, 256, 256);
  wconv_kernel<<<1024, 256, 0, stream>>>(W1, W1t, 8, 256, 1024);
  wconv_kernel<<<1024, 256, 0, stream>>>(W2, W2t, 8, 1024, 256);
  hipMemsetAsync(cnt, 0, (size_t)Nn * 4, stream);
  count_kernel<<<1024, 256, 0, stream>>>(dst, E, cnt);
  scan_kernel<<<1, 256, 0, stream>>>(cnt, rowptr, cursor, Nn);
  fill_kernel<<<1024, 256, 0, stream>>>(src, dst, E, cursor, csrc);

  float* out_hf = (float*)d_out;
  float* out_hs = out_hf + (size_t)Nn * Dm;

  for (int l = 0; l < 4; ++l) {
    const float* hf_s = l ? (const float*)out_hf : hf_in;
    const float* hs_s = l ? (const float*)out_hs : hs_in;
    prep_kernel<<<2048, 256, 0, stream>>>(hf_s, hs_s, x0f, x0b, x1inf, x1inb, Nn * Dm);
    for (int s = 0; s < 2; ++s) {
      int b = s * 4 + l;
      const unsigned short* xb = s ? x1inb : x0b;
      const float* xf = s ? x1inf : x0f;
      // h = xin @ Wg  (bf16 out)
      gemm_kernel<3><<<dim3(128, 2), 256, 0, stream>>>(
          xb, Wgt + (size_t)b * 256 * 256, nullptr, hbuf, nullptr, nullptr, Nn, 256, 256);
      // attention scores
      score_kernel<<<Nn, 256, 0, stream>>>(hbuf, att_src + (size_t)b * 256,
                                           att_dst + (size_t)b * 256, a_s, a_d);
      // segment softmax + aggregate + bias + residual + LN1 -> x1
      agg_kernel<<<Nn, 256, 0, stream>>>(hbuf, a_s, a_d, rowptr, csrc,
                                         bias_gat + (size_t)b * 256, xf,
                                         g1 + (size_t)b * 256, bt1 + (size_t)b * 256,
                                         x1f, x1b);
      // f = relu(x1 @ W1 + b1)  (bf16 out)
      gemm_kernel<1><<<dim3(128, 8), 256, 0, stream>>>(
          x1b, W1t + (size_t)b * 256 * 1024, nullptr, f_b,
          b1 + (size_t)b * 1024, nullptr, Nn, 256, 1024);
      // t = f @ W2 + b2 + x1
      gemm_kernel<2><<<dim3(128, 2), 256, 0, stream>>>(
          f_b, W2t + (size_t)b * 1024 * 256, tf, nullptr,
          b2 + (size_t)b * 256, x1f, Nn, 1024, 256);
      // LN2 -> state
      ln_kernel<<<Nn, 256, 0, stream>>>(tf, g2 + (size_t)b * 256, bt2 + (size_t)b * 256,
                                        s ? out_hs : out_hf);
    }
  }
}

// Round 3
// 1070.389 us; speedup vs baseline: 1.3255x; 1.1439x over previous
//
#include <hip/hip_runtime.h>

#define Nn 16384
#define Dm 256
#define Ff 1024

typedef __attribute__((ext_vector_type(8))) short bf16x8;
typedef __attribute__((ext_vector_type(4))) float f32x4;

typedef const __attribute__((address_space(1))) unsigned int glb_u32;
typedef __attribute__((address_space(3))) unsigned int lds_u32;

__device__ __forceinline__ void async_copy16(const void* g, void* l) {
  __builtin_amdgcn_global_load_lds((glb_u32*)g, (lds_u32*)l, 16, 0, 0);
}

__device__ __forceinline__ unsigned short f2bf(float f) {
  union { float f; unsigned u; } v; v.f = f;
  return (unsigned short)((v.u + 0x7FFFu + ((v.u >> 16) & 1u)) >> 16);
}

__device__ __forceinline__ float bf2f(unsigned short u) {
  union { unsigned u; float f; } v; v.u = ((unsigned)u) << 16;
  return v.f;
}

// ---------------- weight convert + transpose: wt[b][j][k] = bf16(w[b][k][j]) ----------------
__global__ void wconv_kernel(const float* __restrict__ w, unsigned short* __restrict__ wt,
                             int B, int K, int J) {
  size_t total = (size_t)B * K * J;
  size_t kj = (size_t)K * J;
  for (size_t i = (size_t)blockIdx.x * blockDim.x + threadIdx.x; i < total;
       i += (size_t)gridDim.x * blockDim.x) {
    int b = (int)(i / kj);
    int rem = (int)(i - (size_t)b * kj);
    int k = rem / J, j = rem - k * J;
    wt[(size_t)b * kj + (size_t)j * K + k] = f2bf(w[i]);
  }
}

// ---------------- CSR build ----------------
__global__ void count_kernel(const int* __restrict__ dst, int E, int* __restrict__ cnt) {
  for (int e = blockIdx.x * blockDim.x + threadIdx.x; e < E; e += gridDim.x * blockDim.x)
    atomicAdd(&cnt[dst[e]], 1);
}

// per-block exclusive scan (64 blocks x 256), block sums out
__global__ __launch_bounds__(256) void scan1_kernel(const int* __restrict__ cnt,
                                                    int* __restrict__ part,
                                                    int* __restrict__ bsum) {
  __shared__ int sd[256];
  int b = blockIdx.x, tid = threadIdx.x;
  int v = cnt[b * 256 + tid];
  sd[tid] = v;
  __syncthreads();
  for (int offt = 1; offt < 256; offt <<= 1) {
    int t = (tid >= offt) ? sd[tid - offt] : 0;
    __syncthreads();
    sd[tid] += t;
    __syncthreads();
  }
  part[b * 256 + tid] = sd[tid] - v;  // exclusive
  if (tid == 255) bsum[b] = sd[255];
}

// scan 64 block sums (1 block x 64)
__global__ __launch_bounds__(64) void scan2_kernel(const int* __restrict__ bsum,
                                                   int* __restrict__ bbase,
                                                   int* __restrict__ rowptr) {
  __shared__ int sd[64];
  int tid = threadIdx.x;
  int v = bsum[tid];
  sd[tid] = v;
  __syncthreads();
  for (int offt = 1; offt < 64; offt <<= 1) {
    int t = (tid >= offt) ? sd[tid - offt] : 0;
    __syncthreads();
    sd[tid] += t;
    __syncthreads();
  }
  bbase[tid] = sd[tid] - v;
  if (tid == 63) rowptr[Nn] = sd[63];
}

// add block base, write rowptr + cursor
__global__ __launch_bounds__(256) void scan3_kernel(const int* __restrict__ part,
                                                    const int* __restrict__ bbase,
                                                    int* __restrict__ rowptr,
                                                    int* __restrict__ cursor) {
  int b = blockIdx.x, tid = threadIdx.x;
  int v = part[b * 256 + tid] + bbase[b];
  rowptr[b * 256 + tid] = v;
  cursor[b * 256 + tid] = v;
}

__global__ void fill_kernel(const int* __restrict__ src, const int* __restrict__ dst, int E,
                            int* __restrict__ cursor, int* __restrict__ csrc) {
  for (int e = blockIdx.x * blockDim.x + threadIdx.x; e < E; e += gridDim.x * blockDim.x) {
    int pos = atomicAdd(&cursor[dst[e]], 1);
    csrc[pos] = src[e];
  }
}

// ---------------- initial input prep (layer 0 only) ----------------
__global__ void prep_kernel(const float* __restrict__ hf, const float* __restrict__ hs,
                            float* __restrict__ x0f, unsigned short* __restrict__ x0b,
                            float* __restrict__ x1f, unsigned short* __restrict__ x1b, int total) {
  for (int i = blockIdx.x * blockDim.x + threadIdx.x; i < total; i += gridDim.x * blockDim.x) {
    float a = hf[i], b = hs[i];
    float s = a + b;
    x0f[i] = s; x0b[i] = f2bf(s);
    x1f[i] = b; x1b[i] = f2bf(b);
  }
}

// ---------------- bf16 MFMA GEMM: C[M][Ncol] = A[M][K] * Bt[Ncol][K]^T ----------------
// EPI 1: +bias, relu, store bf16. EPI 2: +bias +resid, store f32. EPI 3: plain store bf16.
template <int EPI>
__global__ __launch_bounds__(256, 2) void gemm_kernel(
    const unsigned short* __restrict__ A, const unsigned short* __restrict__ Bt,
    float* __restrict__ outF, unsigned short* __restrict__ outB,
    const float* __restrict__ bias, const float* __restrict__ resid,
    int M, int K, int Ncol) {
  __shared__ __align__(16) unsigned short sA[128 * 32];
  __shared__ __align__(16) unsigned short sB[128 * 32];
  int tid = threadIdx.x;
  int wave = tid >> 6, lane = tid & 63;
  int l16 = lane & 15, lhi = lane >> 4;
  int brow = blockIdx.x, bcol = blockIdx.y;
  int wm = wave >> 1, wn = wave & 1;  // 2x2 waves, wave tile 64x64

  const unsigned short* Ab = A + (size_t)brow * 128 * K;
  const unsigned short* Bb = Bt + (size_t)bcol * 128 * K;

  int ldrow = lane >> 2;
  int ldk = (lane & 3) * 8;

  f32x4 acc[4][4] = {};

  for (int k0 = 0; k0 < K; k0 += 32) {
#pragma unroll
    for (int q = 0; q < 2; ++q) {
      int r0 = wave * 16 + q * 64;
      async_copy16(Ab + (size_t)(r0 + ldrow) * K + k0 + ldk, &sA[r0 * 32]);
      async_copy16(Bb + (size_t)(r0 + ldrow) * K + k0 + ldk, &sB[r0 * 32]);
    }
    __syncthreads();
    bf16x8 af[4], bfr[4];
#pragma unroll
    for (int mi = 0; mi < 4; ++mi)
      af[mi] = *(const bf16x8*)&sA[(wm * 64 + mi * 16 + l16) * 32 + lhi * 8];
#pragma unroll
    for (int ni = 0; ni < 4; ++ni)
      bfr[ni] = *(const bf16x8*)&sB[(wn * 64 + ni * 16 + l16) * 32 + lhi * 8];
#pragma unroll
    for (int mi = 0; mi < 4; ++mi)
#pragma unroll
      for (int ni = 0; ni < 4; ++ni)
        acc[mi][ni] = __builtin_amdgcn_mfma_f32_16x16x32_bf16(af[mi], bfr[ni], acc[mi][ni], 0, 0, 0);
    __syncthreads();
  }

#pragma unroll
  for (int mi = 0; mi < 4; ++mi) {
#pragma unroll
    for (int ni = 0; ni < 4; ++ni) {
#pragma unroll
      for (int j = 0; j < 4; ++j) {
        int r = brow * 128 + wm * 64 + mi * 16 + lhi * 4 + j;
        int c = bcol * 128 + wn * 64 + ni * 16 + l16;
        float v = acc[mi][ni][j];
        if (EPI == 1) {
          v += bias[c];
          v = v > 0.f ? v : 0.f;
          outB[(size_t)r * Ncol + c] = f2bf(v);
        } else if (EPI == 2) {
          v += bias[c] + resid[(size_t)r * Ncol + c];
          outF[(size_t)r * Ncol + c] = v;
        } else {
          outB[(size_t)r * Ncol + c] = f2bf(v);
        }
      }
    }
  }
}

// ---------------- attention scores from bf16 h ----------------
__global__ __launch_bounds__(256) void score_kernel(const unsigned short* __restrict__ hb,
                                                    const float* __restrict__ asr,
                                                    const float* __restrict__ ads,
                                                    float* __restrict__ a_s,
                                                    float* __restrict__ a_d) {
  int n = blockIdx.x, tid = threadIdx.x;
  int head = tid >> 6, lane = tid & 63;
  float hv = bf2f(hb[(size_t)n * 256 + tid]);
  float s1 = hv * asr[tid];
  float s2 = hv * ads[tid];
#pragma unroll
  for (int off = 32; off; off >>= 1) {
    s1 += __shfl_xor(s1, off);
    s2 += __shfl_xor(s2, off);
  }
  if (lane == 0) {
    a_s[n * 4 + head] = s1;
    a_d[n * 4 + head] = s2;
  }
}

// ---------------- fused segment softmax + aggregation + bias + residual + LN1 ----------------
// gather mapping: 8 edge-groups x 32 lanes x 8 channels; 16B loads, 8 edges in flight
__global__ __launch_bounds__(256) void agg_kernel(
    const unsigned short* __restrict__ hb, const float* __restrict__ a_s,
    const float* __restrict__ a_d,
    const int* __restrict__ rowptr, const int* __restrict__ csrc,
    const float* __restrict__ bias, const float* __restrict__ xres,
    const float* __restrict__ g1, const float* __restrict__ bt1,
    float* __restrict__ x1f, unsigned short* __restrict__ x1b) {
  __shared__ float se[4][256];
  __shared__ int ss[256];
  __shared__ float smax[4];
  __shared__ float red[8];
  __shared__ float sacc[8][256];
  __shared__ float sden[8][4];
  int n = blockIdx.x, tid = threadIdx.x;
  int headS = tid >> 6, lane = tid & 63;      // score/LN phase mapping
  int g = tid >> 5, l32 = tid & 31;           // gather mapping
  int hg = l32 >> 3;                          // gather head (channels c0..c0+7 same head)
  int c0 = l32 * 8;
  int beg = rowptr[n], end = rowptr[n + 1];
  float4 adv = *(const float4*)&a_d[n * 4];
  float acc[8] = {};
  float den = 0.f, m = -__builtin_inff();

  for (int base = beg; base < end; base += 256) {
    int cnt = min(256, end - base);
    if (tid < cnt) {
      int s = csrc[base + tid];
      ss[tid] = s;
      float4 asv = *(const float4*)&a_s[s * 4];
      float e0 = asv.x + adv.x; e0 = e0 > 0.f ? e0 : 0.2f * e0;
      float e1 = asv.y + adv.y; e1 = e1 > 0.f ? e1 : 0.2f * e1;
      float e2 = asv.z + adv.z; e2 = e2 > 0.f ? e2 : 0.2f * e2;
      float e3 = asv.w + adv.w; e3 = e3 > 0.f ? e3 : 0.2f * e3;
      se[0][tid] = e0; se[1][tid] = e1; se[2][tid] = e2; se[3][tid] = e3;
    } else {
      se[0][tid] = -__builtin_inff(); se[1][tid] = -__builtin_inff();
      se[2][tid] = -__builtin_inff(); se[3][tid] = -__builtin_inff();
    }
    __syncthreads();
    // wave `headS` reduces chunk max for its head (lane-consecutive reads)
    float v = fmaxf(fmaxf(se[headS][lane], se[headS][lane + 64]),
                    fmaxf(se[headS][lane + 128], se[headS][lane + 192]));
#pragma unroll
    for (int off = 32; off; off >>= 1) v = fmaxf(v, __shfl_xor(v, off));
    if (lane == 0) smax[headS] = fmaxf(m, v);  // m same for all threads tracking headS? no — use chunk max only
    __syncthreads();
    // NOTE: smax[h] currently holds max(m_of_wave_h_lane0, chunkmax). All threads of a head
    // share identical m (same update sequence), so this equals the new running max for head h.
    float mn = smax[hg];
    float r = __expf(m - mn);  // first chunk: m=-inf -> r=0; mn finite (cnt>=1)
#pragma unroll
    for (int j = 0; j < 8; ++j) acc[j] *= r;
    den *= r; m = mn;
    if (tid < cnt) {
      se[0][tid] = __expf(se[0][tid] - smax[0]);
      se[1][tid] = __expf(se[1][tid] - smax[1]);
      se[2][tid] = __expf(se[2][tid] - smax[2]);
      se[3][tid] = __expf(se[3][tid] - smax[3]);
    }
    __syncthreads();
    for (int i = g; i < cnt; i += 8) {
      float w = se[hg][i];
      bf16x8 hv = *(const bf16x8*)(hb + (size_t)ss[i] * 256 + c0);
#pragma unroll
      for (int j = 0; j < 8; ++j)
        acc[j] = fmaf(bf2f((unsigned short)hv[j]), w, acc[j]);
      den += w;
    }
    __syncthreads();
  }

  // cross-group reduction
#pragma unroll
  for (int j = 0; j < 8; ++j) sacc[g][c0 + j] = acc[j];
  if ((l32 & 7) == 0) sden[g][hg] = den;
  __syncthreads();
  float accf = 0.f, denf = 0.f;
#pragma unroll
  for (int g2 = 0; g2 < 8; ++g2) {
    accf += sacc[g2][tid];
    denf += sden[g2][headS];
  }

  float outv = accf / fmaxf(denf, 1e-16f) + bias[tid] + xres[(size_t)n * 256 + tid];
  // LayerNorm over 256 channels
  float s1 = outv, s2 = outv * outv;
#pragma unroll
  for (int off = 32; off; off >>= 1) {
    s1 += __shfl_xor(s1, off);
    s2 += __shfl_xor(s2, off);
  }
  if (lane == 0) { red[headS] = s1; red[4 + headS] = s2; }
  __syncthreads();
  s1 = red[0] + red[1] + red[2] + red[3];
  s2 = red[4] + red[5] + red[6] + red[7];
  float mean = s1 * (1.f / 256.f);
  float var = s2 * (1.f / 256.f) - mean * mean;
  float y = (outv - mean) * rsqrtf(var + 1e-5f) * g1[tid] + bt1[tid];
  x1f[(size_t)n * 256 + tid] = y;
  x1b[(size_t)n * 256 + tid] = f2bf(y);
}

// ---------------- LayerNorm (t -> out), optionally fused next-layer prep ----------------
template <int PREP>
__global__ __launch_bounds__(256) void ln_kernel(const float* __restrict__ t,
                                                 const float* __restrict__ g,
                                                 const float* __restrict__ b,
                                                 float* __restrict__ out,
                                                 const float* __restrict__ other,
                                                 float* __restrict__ x0f,
                                                 unsigned short* __restrict__ x0b,
                                                 float* __restrict__ x1f,
                                                 unsigned short* __restrict__ x1b) {
  __shared__ float red[8];
  int n = blockIdx.x, tid = threadIdx.x;
  int head = tid >> 6, lane = tid & 63;
  size_t idx = (size_t)n * 256 + tid;
  float v = t[idx];
  float s1 = v, s2 = v * v;
#pragma unroll
  for (int off = 32; off; off >>= 1) {
    s1 += __shfl_xor(s1, off);
    s2 += __shfl_xor(s2, off);
  }
  if (lane == 0) { red[head] = s1; red[4 + head] = s2; }
  __syncthreads();
  s1 = red[0] + red[1] + red[2] + red[3];
  s2 = red[4] + red[5] + red[6] + red[7];
  float mean = s1 * (1.f / 256.f);
  float var = s2 * (1.f / 256.f) - mean * mean;
  float y = (v - mean) * rsqrtf(var + 1e-5f) * g[tid] + b[tid];
  out[idx] = y;
  if (PREP) {
    float s = other[idx] + y;  // x0 = hf_new + hs_new
    x0f[idx] = s; x0b[idx] = f2bf(s);
    x1f[idx] = y; x1b[idx] = f2bf(y);
  }
}

extern "C" void kernel_launch(void* const* d_in, const int* in_sizes, int n_in,
                              void* d_out, int out_size, void* d_ws, size_t ws_size,
                              hipStream_t stream) {
  const float* hf_in = (const float*)d_in[0];
  const float* hs_in = (const float*)d_in[1];
  const int* ei = (const int*)d_in[2];
  const int E = in_sizes[2] / 2;
  const float* Wgat = (const float*)d_in[3];
  const float* att_src = (const float*)d_in[4];
  const float* att_dst = (const float*)d_in[5];
  const float* bias_gat = (const float*)d_in[6];
  const float* W1 = (const float*)d_in[7];
  const float* b1 = (const float*)d_in[8];
  const float* W2 = (const float*)d_in[9];
  const float* b2 = (const float*)d_in[10];
  const float* g1 = (const float*)d_in[11];
  const float* bt1 = (const float*)d_in[12];
  const float* g2 = (const float*)d_in[13];
  const float* bt2 = (const float*)d_in[14];
  const int* src = ei;
  const int* dst = ei + E;

  // ---- carve workspace ----
  char* wsp = (char*)d_ws;
  size_t off = 0;
  auto carve = [&](size_t bytes) -> void* {
    void* p = wsp + off;
    off += (bytes + 255) & ~(size_t)255;
    return p;
  };
  unsigned short* Wgt  = (unsigned short*)carve((size_t)8 * 256 * 256 * 2);
  unsigned short* W1t  = (unsigned short*)carve((size_t)8 * 256 * 1024 * 2);
  unsigned short* W2t  = (unsigned short*)carve((size_t)8 * 1024 * 256 * 2);
  int* cnt      = (int*)carve((size_t)Nn * 4);
  int* rowptr   = (int*)carve((size_t)(Nn + 1) * 4);
  int* cursor   = (int*)carve((size_t)Nn * 4);
  int* part     = (int*)carve((size_t)Nn * 4);
  int* bsum     = (int*)carve((size_t)64 * 4);
  int* bbase    = (int*)carve((size_t)64 * 4);
  int* csrc     = (int*)carve((size_t)E * 4);
  float* x0f    = (float*)carve((size_t)Nn * Dm * 4);
  float* x1inf  = (float*)carve((size_t)Nn * Dm * 4);
  unsigned short* x0b   = (unsigned short*)carve((size_t)Nn * Dm * 2);
  unsigned short* x1inb = (unsigned short*)carve((size_t)Nn * Dm * 2);
  unsigned short* hbuf  = (unsigned short*)carve((size_t)Nn * Dm * 2);
  float* tf     = (float*)carve((size_t)Nn * Dm * 4);
  float* a_s    = (float*)carve((size_t)Nn * 4 * 4);
  float* a_d    = (float*)carve((size_t)Nn * 4 * 4);
  float* x1f    = (float*)carve((size_t)Nn * Dm * 4);
  unsigned short* x1b = (unsigned short*)carve((size_t)Nn * Dm * 2);
  unsigned short* f_b = (unsigned short*)carve((size_t)Nn * Ff * 2);
  if (off > ws_size) return;  // workspace too small — fail visibly

  // ---- once per call: weights + CSR ----
  wconv_kernel<<<1024, 256, 0, stream>>>(Wgat, Wgt, 8, 256, 256);
  wconv_kernel<<<1024, 256, 0, stream>>>(W1, W1t, 8, 256, 1024);
  wconv_kernel<<<1024, 256, 0, stream>>>(W2, W2t, 8, 1024, 256);
  hipMemsetAsync(cnt, 0, (size_t)Nn * 4, stream);
  count_kernel<<<1024, 256, 0, stream>>>(dst, E, cnt);
  scan1_kernel<<<64, 256, 0, stream>>>(cnt, part, bsum);
  scan2_kernel<<<1, 64, 0, stream>>>(bsum, bbase, rowptr);
  scan3_kernel<<<64, 256, 0, stream>>>(part, bbase, rowptr, cursor);
  fill_kernel<<<1024, 256, 0, stream>>>(src, dst, E, cursor, csrc);

  float* out_hf = (float*)d_out;
  float* out_hs = out_hf + (size_t)Nn * Dm;

  prep_kernel<<<2048, 256, 0, stream>>>(hf_in, hs_in, x0f, x0b, x1inf, x1inb, Nn * Dm);

  for (int l = 0; l < 4; ++l) {
    for (int s = 0; s < 2; ++s) {
      int b = s * 4 + l;
      const unsigned short* xb = s ? x1inb : x0b;
      const float* xf = s ? x1inf : x0f;
      // h = xin @ Wg  (bf16 out)
      gemm_kernel<3><<<dim3(128, 2), 256, 0, stream>>>(
          xb, Wgt + (size_t)b * 256 * 256, nullptr, hbuf, nullptr, nullptr, Nn, 256, 256);
      // attention scores
      score_kernel<<<Nn, 256, 0, stream>>>(hbuf, att_src + (size_t)b * 256,
                                           att_dst + (size_t)b * 256, a_s, a_d);
      // segment softmax + aggregate + bias + residual + LN1 -> x1
      agg_kernel<<<Nn, 256, 0, stream>>>(hbuf, a_s, a_d, rowptr, csrc,
                                         bias_gat + (size_t)b * 256, xf,
                                         g1 + (size_t)b * 256, bt1 + (size_t)b * 256,
                                         x1f, x1b);
      // f = relu(x1 @ W1 + b1)  (bf16 out)
      gemm_kernel<1><<<dim3(128, 8), 256, 0, stream>>>(
          x1b, W1t + (size_t)b * 256 * 1024, nullptr, f_b,
          b1 + (size_t)b * 1024, nullptr, Nn, 256, 1024);
      // t = f @ W2 + b2 + x1
      gemm_kernel<2><<<dim3(128, 2), 256, 0, stream>>>(
          f_b, W2t + (size_t)b * 1024 * 256, tf, nullptr,
          b2 + (size_t)b * 256, x1f, Nn, 1024, 256);
      // LN2 -> state (+ fused next-layer prep after stream 1, layers 0-2)
      if (s == 1 && l < 3) {
        ln_kernel<1><<<Nn, 256, 0, stream>>>(tf, g2 + (size_t)b * 256, bt2 + (size_t)b * 256,
                                             out_hs, out_hf, x0f, x0b, x1inf, x1inb);
      } else {
        ln_kernel<0><<<Nn, 256, 0, stream>>>(tf, g2 + (size_t)b * 256, bt2 + (size_t)b * 256,
                                             s ? out_hs : out_hf,
                                             nullptr, nullptr, nullptr, nullptr, nullptr);
      }
    }
  }
}

// Round 4
// 947.229 us; speedup vs baseline: 1.4979x; 1.1300x over previous
//
#include <hip/hip_runtime.h>

#define Nn 16384
#define Dm 256
#define Ff 1024

typedef __attribute__((ext_vector_type(8))) short bf16x8;
typedef __attribute__((ext_vector_type(4))) float f32x4;

typedef const __attribute__((address_space(1))) unsigned int glb_u32;
typedef __attribute__((address_space(3))) unsigned int lds_u32;

__device__ __forceinline__ void async_copy16(const void* g, void* l) {
  __builtin_amdgcn_global_load_lds((glb_u32*)g, (lds_u32*)l, 16, 0, 0);
}

__device__ __forceinline__ unsigned short f2bf(float f) {
  union { float f; unsigned u; } v; v.f = f;
  return (unsigned short)((v.u + 0x7FFFu + ((v.u >> 16) & 1u)) >> 16);
}

__device__ __forceinline__ float bf2f(unsigned short u) {
  union { unsigned u; float f; } v; v.u = ((unsigned)u) << 16;
  return v.f;
}

__device__ __forceinline__ float sel4(float4 v, int h) {
  float r = v.x;
  r = (h == 1) ? v.y : r;
  r = (h == 2) ? v.z : r;
  r = (h == 3) ? v.w : r;
  return r;
}

// ---------------- weight convert + transpose: wt[b][j][k] = bf16(w[b][k][j]) ----------------
__global__ void wconv_kernel(const float* __restrict__ w, unsigned short* __restrict__ wt,
                             int B, int K, int J) {
  size_t total = (size_t)B * K * J;
  size_t kj = (size_t)K * J;
  for (size_t i = (size_t)blockIdx.x * blockDim.x + threadIdx.x; i < total;
       i += (size_t)gridDim.x * blockDim.x) {
    int b = (int)(i / kj);
    int rem = (int)(i - (size_t)b * kj);
    int k = rem / J, j = rem - k * J;
    wt[(size_t)b * kj + (size_t)j * K + k] = f2bf(w[i]);
  }
}

// ---------------- CSR build ----------------
__global__ void count_kernel(const int* __restrict__ dst, int E, int* __restrict__ cnt) {
  for (int e = blockIdx.x * blockDim.x + threadIdx.x; e < E; e += gridDim.x * blockDim.x)
    atomicAdd(&cnt[dst[e]], 1);
}

__global__ __launch_bounds__(256) void scan1_kernel(const int* __restrict__ cnt,
                                                    int* __restrict__ part,
                                                    int* __restrict__ bsum) {
  __shared__ int sd[256];
  int b = blockIdx.x, tid = threadIdx.x;
  int v = cnt[b * 256 + tid];
  sd[tid] = v;
  __syncthreads();
  for (int offt = 1; offt < 256; offt <<= 1) {
    int t = (tid >= offt) ? sd[tid - offt] : 0;
    __syncthreads();
    sd[tid] += t;
    __syncthreads();
  }
  part[b * 256 + tid] = sd[tid] - v;  // exclusive
  if (tid == 255) bsum[b] = sd[255];
}

__global__ __launch_bounds__(64) void scan2_kernel(const int* __restrict__ bsum,
                                                   int* __restrict__ bbase,
                                                   int* __restrict__ rowptr) {
  __shared__ int sd[64];
  int tid = threadIdx.x;
  int v = bsum[tid];
  sd[tid] = v;
  __syncthreads();
  for (int offt = 1; offt < 64; offt <<= 1) {
    int t = (tid >= offt) ? sd[tid - offt] : 0;
    __syncthreads();
    sd[tid] += t;
    __syncthreads();
  }
  bbase[tid] = sd[tid] - v;
  if (tid == 63) rowptr[Nn] = sd[63];
}

__global__ __launch_bounds__(256) void scan3_kernel(const int* __restrict__ part,
                                                    const int* __restrict__ bbase,
                                                    int* __restrict__ rowptr,
                                                    int* __restrict__ cursor) {
  int b = blockIdx.x, tid = threadIdx.x;
  int v = part[b * 256 + tid] + bbase[b];
  rowptr[b * 256 + tid] = v;
  cursor[b * 256 + tid] = v;
}

__global__ void fill_kernel(const int* __restrict__ src, const int* __restrict__ dst, int E,
                            int* __restrict__ cursor, int* __restrict__ csrc) {
  for (int e = blockIdx.x * blockDim.x + threadIdx.x; e < E; e += gridDim.x * blockDim.x) {
    int pos = atomicAdd(&cursor[dst[e]], 1);
    csrc[pos] = src[e];
  }
}

// ---------------- initial input prep (layer 0 only) ----------------
__global__ void prep_kernel(const float* __restrict__ hf, const float* __restrict__ hs,
                            float* __restrict__ x0f, unsigned short* __restrict__ x0b,
                            float* __restrict__ x1f, unsigned short* __restrict__ x1b, int total) {
  for (int i = blockIdx.x * blockDim.x + threadIdx.x; i < total; i += gridDim.x * blockDim.x) {
    float a = hf[i], b = hs[i];
    float s = a + b;
    x0f[i] = s; x0b[i] = f2bf(s);
    x1f[i] = b; x1b[i] = f2bf(b);
  }
}

// ---------------- bf16 MFMA GEMM, BN=128: C = A * Bt^T ----------------
// EPI 1: +bias, relu, store bf16. EPI 2: +bias +resid, store f32. EPI 3: plain store bf16.
template <int EPI>
__global__ __launch_bounds__(256, 2) void gemm_kernel(
    const unsigned short* __restrict__ A, const unsigned short* __restrict__ Bt,
    float* __restrict__ outF, unsigned short* __restrict__ outB,
    const float* __restrict__ bias, const float* __restrict__ resid,
    int M, int K, int Ncol) {
  __shared__ __align__(16) unsigned short sA[128 * 32];
  __shared__ __align__(16) unsigned short sB[128 * 32];
  int tid = threadIdx.x;
  int wave = tid >> 6, lane = tid & 63;
  int l16 = lane & 15, lhi = lane >> 4;
  int brow = blockIdx.x, bcol = blockIdx.y;
  int wm = wave >> 1, wn = wave & 1;  // 2x2 waves, wave tile 64x64

  const unsigned short* Ab = A + (size_t)brow * 128 * K;
  const unsigned short* Bb = Bt + (size_t)bcol * 128 * K;

  int ldrow = lane >> 2;
  int ldk = (lane & 3) * 8;

  f32x4 acc[4][4] = {};

  for (int k0 = 0; k0 < K; k0 += 32) {
#pragma unroll
    for (int q = 0; q < 2; ++q) {
      int r0 = wave * 16 + q * 64;
      async_copy16(Ab + (size_t)(r0 + ldrow) * K + k0 + ldk, &sA[r0 * 32]);
      async_copy16(Bb + (size_t)(r0 + ldrow) * K + k0 + ldk, &sB[r0 * 32]);
    }
    __syncthreads();
    bf16x8 af[4], bfr[4];
#pragma unroll
    for (int mi = 0; mi < 4; ++mi)
      af[mi] = *(const bf16x8*)&sA[(wm * 64 + mi * 16 + l16) * 32 + lhi * 8];
#pragma unroll
    for (int ni = 0; ni < 4; ++ni)
      bfr[ni] = *(const bf16x8*)&sB[(wn * 64 + ni * 16 + l16) * 32 + lhi * 8];
#pragma unroll
    for (int mi = 0; mi < 4; ++mi)
#pragma unroll
      for (int ni = 0; ni < 4; ++ni)
        acc[mi][ni] = __builtin_amdgcn_mfma_f32_16x16x32_bf16(af[mi], bfr[ni], acc[mi][ni], 0, 0, 0);
    __syncthreads();
  }

#pragma unroll
  for (int mi = 0; mi < 4; ++mi) {
#pragma unroll
    for (int ni = 0; ni < 4; ++ni) {
#pragma unroll
      for (int j = 0; j < 4; ++j) {
        int r = brow * 128 + wm * 64 + mi * 16 + lhi * 4 + j;
        int c = bcol * 128 + wn * 64 + ni * 16 + l16;
        float v = acc[mi][ni][j];
        if (EPI == 1) {
          v += bias[c];
          v = v > 0.f ? v : 0.f;
          outB[(size_t)r * Ncol + c] = f2bf(v);
        } else if (EPI == 2) {
          v += bias[c] + resid[(size_t)r * Ncol + c];
          outF[(size_t)r * Ncol + c] = v;
        } else {
          outB[(size_t)r * Ncol + c] = f2bf(v);
        }
      }
    }
  }
}

// ---------------- bf16 MFMA GEMM, BM=128 BN=64 (for Ncol=256: 512 blocks = 2/CU) ----------------
template <int EPI>
__global__ __launch_bounds__(256, 2) void gemm64_kernel(
    const unsigned short* __restrict__ A, const unsigned short* __restrict__ Bt,
    float* __restrict__ outF, unsigned short* __restrict__ outB,
    const float* __restrict__ bias, const float* __restrict__ resid,
    int M, int K, int Ncol) {
  __shared__ __align__(16) unsigned short sA[128 * 32];
  __shared__ __align__(16) unsigned short sB[64 * 32];
  int tid = threadIdx.x;
  int wave = tid >> 6, lane = tid & 63;
  int l16 = lane & 15, lhi = lane >> 4;
  int brow = blockIdx.x, bcol = blockIdx.y;
  int wm = wave >> 1, wn = wave & 1;  // wave tile 64x32

  const unsigned short* Ab = A + (size_t)brow * 128 * K;
  const unsigned short* Bb = Bt + (size_t)bcol * 64 * K;

  int ldrow = lane >> 2;
  int ldk = (lane & 3) * 8;

  f32x4 acc[4][2] = {};

  for (int k0 = 0; k0 < K; k0 += 32) {
    int r0 = wave * 16;
    async_copy16(Ab + (size_t)(r0 + ldrow) * K + k0 + ldk, &sA[r0 * 32]);
    async_copy16(Ab + (size_t)(r0 + 64 + ldrow) * K + k0 + ldk, &sA[(r0 + 64) * 32]);
    async_copy16(Bb + (size_t)(r0 + ldrow) * K + k0 + ldk, &sB[r0 * 32]);
    __syncthreads();
    bf16x8 af[4], bfr[2];
#pragma unroll
    for (int mi = 0; mi < 4; ++mi)
      af[mi] = *(const bf16x8*)&sA[(wm * 64 + mi * 16 + l16) * 32 + lhi * 8];
#pragma unroll
    for (int ni = 0; ni < 2; ++ni)
      bfr[ni] = *(const bf16x8*)&sB[(wn * 32 + ni * 16 + l16) * 32 + lhi * 8];
#pragma unroll
    for (int mi = 0; mi < 4; ++mi)
#pragma unroll
      for (int ni = 0; ni < 2; ++ni)
        acc[mi][ni] = __builtin_amdgcn_mfma_f32_16x16x32_bf16(af[mi], bfr[ni], acc[mi][ni], 0, 0, 0);
    __syncthreads();
  }

#pragma unroll
  for (int mi = 0; mi < 4; ++mi) {
#pragma unroll
    for (int ni = 0; ni < 2; ++ni) {
#pragma unroll
      for (int j = 0; j < 4; ++j) {
        int r = brow * 128 + wm * 64 + mi * 16 + lhi * 4 + j;
        int c = bcol * 64 + wn * 32 + ni * 16 + l16;
        float v = acc[mi][ni][j];
        if (EPI == 1) {
          v += bias[c];
          v = v > 0.f ? v : 0.f;
          outB[(size_t)r * Ncol + c] = f2bf(v);
        } else if (EPI == 2) {
          v += bias[c] + resid[(size_t)r * Ncol + c];
          outF[(size_t)r * Ncol + c] = v;
        } else {
          outB[(size_t)r * Ncol + c] = f2bf(v);
        }
      }
    }
  }
}

// ---------------- attention scores from bf16 h ----------------
__global__ __launch_bounds__(256) void score_kernel(const unsigned short* __restrict__ hb,
                                                    const float* __restrict__ asr,
                                                    const float* __restrict__ ads,
                                                    float* __restrict__ a_s,
                                                    float* __restrict__ a_d) {
  int n = blockIdx.x, tid = threadIdx.x;
  int head = tid >> 6, lane = tid & 63;
  float hv = bf2f(hb[(size_t)n * 256 + tid]);
  float s1 = hv * asr[tid];
  float s2 = hv * ads[tid];
#pragma unroll
  for (int off = 32; off; off >>= 1) {
    s1 += __shfl_xor(s1, off);
    s2 += __shfl_xor(s2, off);
  }
  if (lane == 0) {
    a_s[n * 4 + head] = s1;
    a_d[n * 4 + head] = s2;
  }
}

// ---------------- wave-per-node fused softmax + aggregation + bias + residual + LN1 ----------------
// 4 waves/block, node = blockIdx*4 + wave. Barrier-free (waves independent).
// PV: 2 edges/iter; lane = parity(lane>>5) edge, channels c0 = (lane&31)*8 (16B gathers).
__global__ __launch_bounds__(256) void agg_kernel(
    const unsigned short* __restrict__ hb, const float* __restrict__ a_s,
    const float* __restrict__ a_d,
    const int* __restrict__ rowptr, const int* __restrict__ csrc,
    const float* __restrict__ bias, const float* __restrict__ xres,
    const float* __restrict__ g1, const float* __restrict__ bt1,
    float* __restrict__ x1f, unsigned short* __restrict__ x1b) {
  __shared__ float sw[4][320];  // [wave][slot*5 + head]  (stride 5: conflict-free)
  __shared__ int ssrc[4][64];
  int wave = threadIdx.x >> 6, lane = threadIdx.x & 63;
  int n = blockIdx.x * 4 + wave;
  int l32 = lane & 31;
  int par = lane >> 5;         // edge parity
  int hch = l32 >> 3;          // head of my channel block
  int c0 = l32 * 8;            // my 8 channels
  int beg = rowptr[n], end = rowptr[n + 1];
  float4 adv = *(const float4*)&a_d[n * 4];
  const float NI = -__builtin_inff();
  float4 m4 = {NI, NI, NI, NI};
  float acc[8] = {};
  float den = 0.f;

  for (int base = beg; base < end; base += 64) {
    int cnt = min(64, end - base);
    // --- score phase: lane = edge slot ---
    float4 ev = {NI, NI, NI, NI};
    if (lane < cnt) {
      int s = csrc[base + lane];
      ssrc[wave][lane] = s;
      float4 as = *(const float4*)&a_s[s * 4];
      float e0 = as.x + adv.x; ev.x = e0 > 0.f ? e0 : 0.2f * e0;
      float e1 = as.y + adv.y; ev.y = e1 > 0.f ? e1 : 0.2f * e1;
      float e2 = as.z + adv.z; ev.z = e2 > 0.f ? e2 : 0.2f * e2;
      float e3 = as.w + adv.w; ev.w = e3 > 0.f ? e3 : 0.2f * e3;
    }
    // per-head chunk max across 64 lanes
    float4 mv = ev;
#pragma unroll
    for (int off = 32; off; off >>= 1) {
      mv.x = fmaxf(mv.x, __shfl_xor(mv.x, off));
      mv.y = fmaxf(mv.y, __shfl_xor(mv.y, off));
      mv.z = fmaxf(mv.z, __shfl_xor(mv.z, off));
      mv.w = fmaxf(mv.w, __shfl_xor(mv.w, off));
    }
    float4 m4n;
    m4n.x = fmaxf(m4.x, mv.x); m4n.y = fmaxf(m4.y, mv.y);
    m4n.z = fmaxf(m4.z, mv.z); m4n.w = fmaxf(m4.w, mv.w);
    // rescale my channels (first chunk: exp(-inf)=0)
    float rm = __expf(sel4(m4, hch) - sel4(m4n, hch));
#pragma unroll
    for (int j = 0; j < 8; ++j) acc[j] *= rm;
    den *= rm;
    // edge weights -> LDS
    if (lane < cnt) {
      float* swl = &sw[wave][lane * 5];
      swl[0] = __expf(ev.x - m4n.x);
      swl[1] = __expf(ev.y - m4n.y);
      swl[2] = __expf(ev.z - m4n.z);
      swl[3] = __expf(ev.w - m4n.w);
    }
    m4 = m4n;
    __builtin_amdgcn_wave_barrier();  // same-wave LDS ops are in-order; fence the compiler
    // --- PV phase: 2 edges per iteration ---
    for (int i = par; i < cnt; i += 2) {
      float w = sw[wave][i * 5 + hch];
      int s_i = ssrc[wave][i];
      bf16x8 hv = *(const bf16x8*)(hb + (size_t)s_i * 256 + c0);
#pragma unroll
      for (int j = 0; j < 8; ++j)
        acc[j] = fmaf(bf2f((unsigned short)hv[j]), w, acc[j]);
      den += w;
    }
    __builtin_amdgcn_wave_barrier();
  }

  // combine edge parities (lane ^ 32 holds same channels, other parity)
#pragma unroll
  for (int j = 0; j < 8; ++j) acc[j] += __shfl_xor(acc[j], 32);
  den += __shfl_xor(den, 32);

  float invden = 1.f / fmaxf(den, 1e-16f);
  float outv[8];
  float s1 = 0.f, s2 = 0.f;
#pragma unroll
  for (int j = 0; j < 8; ++j) {
    float v = acc[j] * invden + bias[c0 + j] + xres[(size_t)n * 256 + c0 + j];
    outv[j] = v;
    s1 += v;
    s2 += v * v;
  }
  // LN reduce over the 32-lane half (halves hold identical data)
#pragma unroll
  for (int off = 16; off; off >>= 1) {
    s1 += __shfl_xor(s1, off);
    s2 += __shfl_xor(s2, off);
  }
  float mean = s1 * (1.f / 256.f);
  float var = s2 * (1.f / 256.f) - mean * mean;
  float rst = rsqrtf(var + 1e-5f);
  if (par == 0) {
    float4 y0, y1;
    unsigned short yb[8];
#pragma unroll
    for (int j = 0; j < 8; ++j) {
      float y = (outv[j] - mean) * rst * g1[c0 + j] + bt1[c0 + j];
      if (j < 4) ((float*)&y0)[j] = y; else ((float*)&y1)[j - 4] = y;
      yb[j] = f2bf(y);
    }
    size_t idx = (size_t)n * 256 + c0;
    *(float4*)&x1f[idx] = y0;
    *(float4*)&x1f[idx + 4] = y1;
    *(bf16x8*)&x1b[idx] = *(bf16x8*)yb;
  }
}

// ---------------- LayerNorm (t -> out), optionally fused next-layer prep ----------------
template <int PREP>
__global__ __launch_bounds__(256) void ln_kernel(const float* __restrict__ t,
                                                 const float* __restrict__ g,
                                                 const float* __restrict__ b,
                                                 float* __restrict__ out,
                                                 const float* __restrict__ other,
                                                 float* __restrict__ x0f,
                                                 unsigned short* __restrict__ x0b,
                                                 float* __restrict__ x1f,
                                                 unsigned short* __restrict__ x1b) {
  __shared__ float red[8];
  int n = blockIdx.x, tid = threadIdx.x;
  int head = tid >> 6, lane = tid & 63;
  size_t idx = (size_t)n * 256 + tid;
  float v = t[idx];
  float s1 = v, s2 = v * v;
#pragma unroll
  for (int off = 32; off; off >>= 1) {
    s1 += __shfl_xor(s1, off);
    s2 += __shfl_xor(s2, off);
  }
  if (lane == 0) { red[head] = s1; red[4 + head] = s2; }
  __syncthreads();
  s1 = red[0] + red[1] + red[2] + red[3];
  s2 = red[4] + red[5] + red[6] + red[7];
  float mean = s1 * (1.f / 256.f);
  float var = s2 * (1.f / 256.f) - mean * mean;
  float y = (v - mean) * rsqrtf(var + 1e-5f) * g[tid] + b[tid];
  out[idx] = y;
  if (PREP) {
    float s = other[idx] + y;  // x0 = hf_new + hs_new
    x0f[idx] = s; x0b[idx] = f2bf(s);
    x1f[idx] = y; x1b[idx] = f2bf(y);
  }
}

extern "C" void kernel_launch(void* const* d_in, const int* in_sizes, int n_in,
                              void* d_out, int out_size, void* d_ws, size_t ws_size,
                              hipStream_t stream) {
  const float* hf_in = (const float*)d_in[0];
  const float* hs_in = (const float*)d_in[1];
  const int* ei = (const int*)d_in[2];
  const int E = in_sizes[2] / 2;
  const float* Wgat = (const float*)d_in[3];
  const float* att_src = (const float*)d_in[4];
  const float* att_dst = (const float*)d_in[5];
  const float* bias_gat = (const float*)d_in[6];
  const float* W1 = (const float*)d_in[7];
  const float* b1 = (const float*)d_in[8];
  const float* W2 = (const float*)d_in[9];
  const float* b2 = (const float*)d_in[10];
  const float* g1 = (const float*)d_in[11];
  const float* bt1 = (const float*)d_in[12];
  const float* g2 = (const float*)d_in[13];
  const float* bt2 = (const float*)d_in[14];
  const int* src = ei;
  const int* dst = ei + E;

  // ---- carve workspace ----
  char* wsp = (char*)d_ws;
  size_t off = 0;
  auto carve = [&](size_t bytes) -> void* {
    void* p = wsp + off;
    off += (bytes + 255) & ~(size_t)255;
    return p;
  };
  unsigned short* Wgt  = (unsigned short*)carve((size_t)8 * 256 * 256 * 2);
  unsigned short* W1t  = (unsigned short*)carve((size_t)8 * 256 * 1024 * 2);
  unsigned short* W2t  = (unsigned short*)carve((size_t)8 * 1024 * 256 * 2);
  int* cnt      = (int*)carve((size_t)Nn * 4);
  int* rowptr   = (int*)carve((size_t)(Nn + 1) * 4);
  int* cursor   = (int*)carve((size_t)Nn * 4);
  int* part     = (int*)carve((size_t)Nn * 4);
  int* bsum     = (int*)carve((size_t)64 * 4);
  int* bbase    = (int*)carve((size_t)64 * 4);
  int* csrc     = (int*)carve((size_t)E * 4);
  float* x0f    = (float*)carve((size_t)Nn * Dm * 4);
  float* x1inf  = (float*)carve((size_t)Nn * Dm * 4);
  unsigned short* x0b   = (unsigned short*)carve((size_t)Nn * Dm * 2);
  unsigned short* x1inb = (unsigned short*)carve((size_t)Nn * Dm * 2);
  unsigned short* hbuf  = (unsigned short*)carve((size_t)Nn * Dm * 2);
  float* tf     = (float*)carve((size_t)Nn * Dm * 4);
  float* a_s    = (float*)carve((size_t)Nn * 4 * 4);
  float* a_d    = (float*)carve((size_t)Nn * 4 * 4);
  float* x1f    = (float*)carve((size_t)Nn * Dm * 4);
  unsigned short* x1b = (unsigned short*)carve((size_t)Nn * Dm * 2);
  unsigned short* f_b = (unsigned short*)carve((size_t)Nn * Ff * 2);
  if (off > ws_size) return;  // workspace too small — fail visibly

  // ---- once per call: weights + CSR ----
  wconv_kernel<<<1024, 256, 0, stream>>>(Wgat, Wgt, 8, 256, 256);
  wconv_kernel<<<1024, 256, 0, stream>>>(W1, W1t, 8, 256, 1024);
  wconv_kernel<<<1024, 256, 0, stream>>>(W2, W2t, 8, 1024, 256);
  hipMemsetAsync(cnt, 0, (size_t)Nn * 4, stream);
  count_kernel<<<1024, 256, 0, stream>>>(dst, E, cnt);
  scan1_kernel<<<64, 256, 0, stream>>>(cnt, part, bsum);
  scan2_kernel<<<1, 64, 0, stream>>>(bsum, bbase, rowptr);
  scan3_kernel<<<64, 256, 0, stream>>>(part, bbase, rowptr, cursor);
  fill_kernel<<<1024, 256, 0, stream>>>(src, dst, E, cursor, csrc);

  float* out_hf = (float*)d_out;
  float* out_hs = out_hf + (size_t)Nn * Dm;

  prep_kernel<<<2048, 256, 0, stream>>>(hf_in, hs_in, x0f, x0b, x1inf, x1inb, Nn * Dm);

  for (int l = 0; l < 4; ++l) {
    for (int s = 0; s < 2; ++s) {
      int b = s * 4 + l;
      const unsigned short* xb = s ? x1inb : x0b;
      const float* xf = s ? x1inf : x0f;
      // h = xin @ Wg  (bf16 out) — BN=64 tiles, 512 blocks
      gemm64_kernel<3><<<dim3(128, 4), 256, 0, stream>>>(
          xb, Wgt + (size_t)b * 256 * 256, nullptr, hbuf, nullptr, nullptr, Nn, 256, 256);
      // attention scores
      score_kernel<<<Nn, 256, 0, stream>>>(hbuf, att_src + (size_t)b * 256,
                                           att_dst + (size_t)b * 256, a_s, a_d);
      // segment softmax + aggregate + bias + residual + LN1 -> x1 (wave per node)
      agg_kernel<<<Nn / 4, 256, 0, stream>>>(hbuf, a_s, a_d, rowptr, csrc,
                                             bias_gat + (size_t)b * 256, xf,
                                             g1 + (size_t)b * 256, bt1 + (size_t)b * 256,
                                             x1f, x1b);
      // f = relu(x1 @ W1 + b1)  (bf16 out)
      gemm_kernel<1><<<dim3(128, 8), 256, 0, stream>>>(
          x1b, W1t + (size_t)b * 256 * 1024, nullptr, f_b,
          b1 + (size_t)b * 1024, nullptr, Nn, 256, 1024);
      // t = f @ W2 + b2 + x1 — BN=64 tiles
      gemm64_kernel<2><<<dim3(128, 4), 256, 0, stream>>>(
          f_b, W2t + (size_t)b * 1024 * 256, tf, nullptr,
          b2 + (size_t)b * 256, x1f, Nn, 1024, 256);
      // LN2 -> state (+ fused next-layer prep after stream 1, layers 0-2)
      if (s == 1 && l < 3) {
        ln_kernel<1><<<Nn, 256, 0, stream>>>(tf, g2 + (size_t)b * 256, bt2 + (size_t)b * 256,
                                             out_hs, out_hf, x0f, x0b, x1inf, x1inb);
      } else {
        ln_kernel<0><<<Nn, 256, 0, stream>>>(tf, g2 + (size_t)b * 256, bt2 + (size_t)b * 256,
                                             s ? out_hs : out_hf,
                                             nullptr, nullptr, nullptr, nullptr, nullptr);
      }
    }
  }
}

// Round 5
// 840.606 us; speedup vs baseline: 1.6879x; 1.1268x over previous
//
#include <hip/hip_runtime.h>

#define Nn 16384
#define Dm 256
#define Ff 1024

typedef __attribute__((ext_vector_type(8))) short bf16x8;
typedef __attribute__((ext_vector_type(4))) float f32x4;

typedef const __attribute__((address_space(1))) unsigned int glb_u32;
typedef __attribute__((address_space(3))) unsigned int lds_u32;

__device__ __forceinline__ void async_copy16(const void* g, void* l) {
  __builtin_amdgcn_global_load_lds((glb_u32*)g, (lds_u32*)l, 16, 0, 0);
}

__device__ __forceinline__ unsigned short f2bf(float f) {
  union { float f; unsigned u; } v; v.f = f;
  return (unsigned short)((v.u + 0x7FFFu + ((v.u >> 16) & 1u)) >> 16);
}

__device__ __forceinline__ float bf2f(unsigned short u) {
  union { unsigned u; float f; } v; v.u = ((unsigned)u) << 16;
  return v.f;
}

__device__ __forceinline__ float sel4(float4 v, int h) {
  float r = v.x;
  r = (h == 1) ? v.y : r;
  r = (h == 2) ? v.z : r;
  r = (h == 3) ? v.w : r;
  return r;
}

// ---------------- weight convert + transpose: wt[b][j][k] = bf16(w[b][k][j]) ----------------
__global__ void wconv_kernel(const float* __restrict__ w, unsigned short* __restrict__ wt,
                             int B, int K, int J) {
  size_t total = (size_t)B * K * J;
  size_t kj = (size_t)K * J;
  for (size_t i = (size_t)blockIdx.x * blockDim.x + threadIdx.x; i < total;
       i += (size_t)gridDim.x * blockDim.x) {
    int b = (int)(i / kj);
    int rem = (int)(i - (size_t)b * kj);
    int k = rem / J, j = rem - k * J;
    wt[(size_t)b * kj + (size_t)j * K + k] = f2bf(w[i]);
  }
}

// ---------------- CSR build ----------------
__global__ void count_kernel(const int* __restrict__ dst, int E, int* __restrict__ cnt) {
  for (int e = blockIdx.x * blockDim.x + threadIdx.x; e < E; e += gridDim.x * blockDim.x)
    atomicAdd(&cnt[dst[e]], 1);
}

__global__ __launch_bounds__(256) void scan1_kernel(const int* __restrict__ cnt,
                                                    int* __restrict__ part,
                                                    int* __restrict__ bsum) {
  __shared__ int sd[256];
  int b = blockIdx.x, tid = threadIdx.x;
  int v = cnt[b * 256 + tid];
  sd[tid] = v;
  __syncthreads();
  for (int offt = 1; offt < 256; offt <<= 1) {
    int t = (tid >= offt) ? sd[tid - offt] : 0;
    __syncthreads();
    sd[tid] += t;
    __syncthreads();
  }
  part[b * 256 + tid] = sd[tid] - v;  // exclusive
  if (tid == 255) bsum[b] = sd[255];
}

__global__ __launch_bounds__(64) void scan2_kernel(const int* __restrict__ bsum,
                                                   int* __restrict__ bbase,
                                                   int* __restrict__ rowptr) {
  __shared__ int sd[64];
  int tid = threadIdx.x;
  int v = bsum[tid];
  sd[tid] = v;
  __syncthreads();
  for (int offt = 1; offt < 64; offt <<= 1) {
    int t = (tid >= offt) ? sd[tid - offt] : 0;
    __syncthreads();
    sd[tid] += t;
    __syncthreads();
  }
  bbase[tid] = sd[tid] - v;
  if (tid == 63) rowptr[Nn] = sd[63];
}

__global__ __launch_bounds__(256) void scan3_kernel(const int* __restrict__ part,
                                                    const int* __restrict__ bbase,
                                                    int* __restrict__ rowptr,
                                                    int* __restrict__ cursor) {
  int b = blockIdx.x, tid = threadIdx.x;
  int v = part[b * 256 + tid] + bbase[b];
  rowptr[b * 256 + tid] = v;
  cursor[b * 256 + tid] = v;
}

__global__ void fill_kernel(const int* __restrict__ src, const int* __restrict__ dst, int E,
                            int* __restrict__ cursor, int* __restrict__ csrc) {
  for (int e = blockIdx.x * blockDim.x + threadIdx.x; e < E; e += gridDim.x * blockDim.x) {
    int pos = atomicAdd(&cursor[dst[e]], 1);
    csrc[pos] = src[e];
  }
}

// ---------------- initial input prep (layer 0): x01f[0]=hf+hs, x01f[1]=hs ----------------
__global__ void prep_kernel(const float* __restrict__ hf, const float* __restrict__ hs,
                            float* __restrict__ x01f, unsigned short* __restrict__ x01b,
                            int total) {
  const size_t ZS = (size_t)Nn * Dm;
  for (int i = blockIdx.x * blockDim.x + threadIdx.x; i < total; i += gridDim.x * blockDim.x) {
    float a = hf[i], b = hs[i];
    float s = a + b;
    x01f[i] = s; x01b[i] = f2bf(s);
    x01f[ZS + i] = b; x01b[ZS + i] = f2bf(b);
  }
}

// ---------------- proj GEMM (both streams, z=blockIdx.z) + fused attention scores ----------------
// C[z] = X[z] @ Wg[z]^T (bf16 out);  a_s[z][r][bcol], a_d[z][r][bcol] from f32 accumulators.
__global__ __launch_bounds__(256, 2) void proj_kernel(
    const unsigned short* __restrict__ xib, const unsigned short* __restrict__ Wgt_l,
    unsigned short* __restrict__ hbuf2, const float* __restrict__ asr_l,
    const float* __restrict__ ads_l, float* __restrict__ a_s2, float* __restrict__ a_d2) {
  __shared__ __align__(16) unsigned short sA[128 * 32];
  __shared__ __align__(16) unsigned short sB[64 * 32];
  const int K = 256;
  const size_t ZS = (size_t)Nn * Dm;
  int tid = threadIdx.x;
  int wave = tid >> 6, lane = tid & 63;
  int l16 = lane & 15, lhi = lane >> 4;
  int brow = blockIdx.x, bcol = blockIdx.y, z = blockIdx.z;
  int wm = wave >> 1, wn = wave & 1;  // wave tile 64x32

  const unsigned short* Ab = xib + z * ZS + (size_t)brow * 128 * K;
  const unsigned short* Bb = Wgt_l + (size_t)z * 4 * 65536 + (size_t)bcol * 64 * K;

  int ldrow = lane >> 2;
  int ldk = (lane & 3) * 8;

  f32x4 acc[4][2] = {};

  for (int k0 = 0; k0 < K; k0 += 32) {
    int r0 = wave * 16;
    async_copy16(Ab + (size_t)(r0 + ldrow) * K + k0 + ldk, &sA[r0 * 32]);
    async_copy16(Ab + (size_t)(r0 + 64 + ldrow) * K + k0 + ldk, &sA[(r0 + 64) * 32]);
    async_copy16(Bb + (size_t)(r0 + ldrow) * K + k0 + ldk, &sB[r0 * 32]);
    __syncthreads();
    bf16x8 af[4], bfr[2];
#pragma unroll
    for (int mi = 0; mi < 4; ++mi)
      af[mi] = *(const bf16x8*)&sA[(wm * 64 + mi * 16 + l16) * 32 + lhi * 8];
#pragma unroll
    for (int ni = 0; ni < 2; ++ni)
      bfr[ni] = *(const bf16x8*)&sB[(wn * 32 + ni * 16 + l16) * 32 + lhi * 8];
#pragma unroll
    for (int mi = 0; mi < 4; ++mi)
#pragma unroll
      for (int ni = 0; ni < 2; ++ni)
        acc[mi][ni] = __builtin_amdgcn_mfma_f32_16x16x32_bf16(af[mi], bfr[ni], acc[mi][ni], 0, 0, 0);
    __syncthreads();
  }

  // ---- epilogue: C store (bf16) + per-row attention-score partials ----
  unsigned short* hb = hbuf2 + z * ZS;
  const float* asr_p = asr_l + z * 1024 + bcol * 64;
  const float* ads_p = ads_l + z * 1024 + bcol * 64;
  float as0 = asr_p[wn * 32 + l16],      ad0 = ads_p[wn * 32 + l16];
  float as1 = asr_p[wn * 32 + 16 + l16], ad1 = ads_p[wn * 32 + 16 + l16];
  float* sredS = (float*)sA;        // [wm][wn][64] = 256 floats
  float* sredD = (float*)sA + 256;  // (sA dead after K loop; last iter ended in syncthreads)

#pragma unroll
  for (int mi = 0; mi < 4; ++mi) {
#pragma unroll
    for (int j = 0; j < 4; ++j) {
      int r = brow * 128 + wm * 64 + mi * 16 + lhi * 4 + j;
      float v0 = acc[mi][0][j], v1 = acc[mi][1][j];
      hb[(size_t)r * 256 + bcol * 64 + wn * 32 + l16] = f2bf(v0);
      hb[(size_t)r * 256 + bcol * 64 + wn * 32 + 16 + l16] = f2bf(v1);
      float ps = v0 * as0 + v1 * as1;
      float pd = v0 * ad0 + v1 * ad1;
#pragma unroll
      for (int off = 1; off < 16; off <<= 1) {
        ps += __shfl_xor(ps, off);
        pd += __shfl_xor(pd, off);
      }
      if (l16 == 0) {
        int rl = mi * 16 + lhi * 4 + j;  // row within wave tile [0,64)
        sredS[wm * 128 + wn * 64 + rl] = ps;
        sredD[wm * 128 + wn * 64 + rl] = pd;
      }
    }
  }
  __syncthreads();
  if (tid < 128) {
    int w = tid >> 6, rl = tid & 63;
    float s = sredS[w * 128 + rl] + sredS[w * 128 + 64 + rl];
    float d = sredD[w * 128 + rl] + sredD[w * 128 + 64 + rl];
    int row = brow * 128 + tid;
    a_s2[(size_t)z * Nn * 4 + row * 4 + bcol] = s;
    a_d2[(size_t)z * Nn * 4 + row * 4 + bcol] = d;
  }
}

// ---------------- bf16 MFMA GEMM, BN=128 (FFN1): +bias, relu, store bf16 ----------------
__global__ __launch_bounds__(256, 2) void gemm_kernel(
    const unsigned short* __restrict__ A, const unsigned short* __restrict__ Bt,
    unsigned short* __restrict__ outB, const float* __restrict__ bias,
    int M, int K, int Ncol) {
  __shared__ __align__(16) unsigned short sA[128 * 32];
  __shared__ __align__(16) unsigned short sB[128 * 32];
  int tid = threadIdx.x;
  int wave = tid >> 6, lane = tid & 63;
  int l16 = lane & 15, lhi = lane >> 4;
  int brow = blockIdx.x, bcol = blockIdx.y;
  int wm = wave >> 1, wn = wave & 1;  // 2x2 waves, wave tile 64x64

  const unsigned short* Ab = A + (size_t)brow * 128 * K;
  const unsigned short* Bb = Bt + (size_t)bcol * 128 * K;

  int ldrow = lane >> 2;
  int ldk = (lane & 3) * 8;

  f32x4 acc[4][4] = {};

  for (int k0 = 0; k0 < K; k0 += 32) {
#pragma unroll
    for (int q = 0; q < 2; ++q) {
      int r0 = wave * 16 + q * 64;
      async_copy16(Ab + (size_t)(r0 + ldrow) * K + k0 + ldk, &sA[r0 * 32]);
      async_copy16(Bb + (size_t)(r0 + ldrow) * K + k0 + ldk, &sB[r0 * 32]);
    }
    __syncthreads();
    bf16x8 af[4], bfr[4];
#pragma unroll
    for (int mi = 0; mi < 4; ++mi)
      af[mi] = *(const bf16x8*)&sA[(wm * 64 + mi * 16 + l16) * 32 + lhi * 8];
#pragma unroll
    for (int ni = 0; ni < 4; ++ni)
      bfr[ni] = *(const bf16x8*)&sB[(wn * 64 + ni * 16 + l16) * 32 + lhi * 8];
#pragma unroll
    for (int mi = 0; mi < 4; ++mi)
#pragma unroll
      for (int ni = 0; ni < 4; ++ni)
        acc[mi][ni] = __builtin_amdgcn_mfma_f32_16x16x32_bf16(af[mi], bfr[ni], acc[mi][ni], 0, 0, 0);
    __syncthreads();
  }

#pragma unroll
  for (int mi = 0; mi < 4; ++mi) {
#pragma unroll
    for (int ni = 0; ni < 4; ++ni) {
#pragma unroll
      for (int j = 0; j < 4; ++j) {
        int r = brow * 128 + wm * 64 + mi * 16 + lhi * 4 + j;
        int c = bcol * 128 + wn * 64 + ni * 16 + l16;
        float v = acc[mi][ni][j] + bias[c];
        v = v > 0.f ? v : 0.f;
        outB[(size_t)r * Ncol + c] = f2bf(v);
      }
    }
  }
}

// ---------------- bf16 MFMA GEMM, BM=128 BN=64 (FFN2): +bias +resid, store f32 ----------------
__global__ __launch_bounds__(256, 2) void gemm64_kernel(
    const unsigned short* __restrict__ A, const unsigned short* __restrict__ Bt,
    float* __restrict__ outF, const float* __restrict__ bias,
    const float* __restrict__ resid, int M, int K, int Ncol) {
  __shared__ __align__(16) unsigned short sA[128 * 32];
  __shared__ __align__(16) unsigned short sB[64 * 32];
  int tid = threadIdx.x;
  int wave = tid >> 6, lane = tid & 63;
  int l16 = lane & 15, lhi = lane >> 4;
  int brow = blockIdx.x, bcol = blockIdx.y;
  int wm = wave >> 1, wn = wave & 1;  // wave tile 64x32

  const unsigned short* Ab = A + (size_t)brow * 128 * K;
  const unsigned short* Bb = Bt + (size_t)bcol * 64 * K;

  int ldrow = lane >> 2;
  int ldk = (lane & 3) * 8;

  f32x4 acc[4][2] = {};

  for (int k0 = 0; k0 < K; k0 += 32) {
    int r0 = wave * 16;
    async_copy16(Ab + (size_t)(r0 + ldrow) * K + k0 + ldk, &sA[r0 * 32]);
    async_copy16(Ab + (size_t)(r0 + 64 + ldrow) * K + k0 + ldk, &sA[(r0 + 64) * 32]);
    async_copy16(Bb + (size_t)(r0 + ldrow) * K + k0 + ldk, &sB[r0 * 32]);
    __syncthreads();
    bf16x8 af[4], bfr[2];
#pragma unroll
    for (int mi = 0; mi < 4; ++mi)
      af[mi] = *(const bf16x8*)&sA[(wm * 64 + mi * 16 + l16) * 32 + lhi * 8];
#pragma unroll
    for (int ni = 0; ni < 2; ++ni)
      bfr[ni] = *(const bf16x8*)&sB[(wn * 32 + ni * 16 + l16) * 32 + lhi * 8];
#pragma unroll
    for (int mi = 0; mi < 4; ++mi)
#pragma unroll
      for (int ni = 0; ni < 2; ++ni)
        acc[mi][ni] = __builtin_amdgcn_mfma_f32_16x16x32_bf16(af[mi], bfr[ni], acc[mi][ni], 0, 0, 0);
    __syncthreads();
  }

#pragma unroll
  for (int mi = 0; mi < 4; ++mi) {
#pragma unroll
    for (int ni = 0; ni < 2; ++ni) {
#pragma unroll
      for (int j = 0; j < 4; ++j) {
        int r = brow * 128 + wm * 64 + mi * 16 + lhi * 4 + j;
        int c = bcol * 64 + wn * 32 + ni * 16 + l16;
        float v = acc[mi][ni][j] + bias[c] + resid[(size_t)r * Ncol + c];
        outF[(size_t)r * Ncol + c] = v;
      }
    }
  }
}

// ---------------- wave-per-node fused softmax + aggregation + bias + residual + LN1 ----------------
// grid (Nn/4, 2): y = stream. 4 waves/block, node = blockIdx.x*4 + wave. Barrier-free.
__global__ __launch_bounds__(256) void agg_kernel(
    const unsigned short* __restrict__ hbuf2, const float* __restrict__ a_s2,
    const float* __restrict__ a_d2,
    const int* __restrict__ rowptr, const int* __restrict__ csrc,
    const float* __restrict__ bias_l, const float* __restrict__ x01f,
    const float* __restrict__ g1_l, const float* __restrict__ bt1_l,
    float* __restrict__ x1f2, unsigned short* __restrict__ x1b2) {
  __shared__ float sw[4][320];  // [wave][slot*5 + head]  (stride 5: conflict-free)
  __shared__ int ssrc[4][64];
  const size_t ZS = (size_t)Nn * Dm;
  int z = blockIdx.y;
  const unsigned short* hb = hbuf2 + z * ZS;
  const float* a_s = a_s2 + (size_t)z * Nn * 4;
  const float* a_d = a_d2 + (size_t)z * Nn * 4;
  const float* bias = bias_l + z * 1024;
  const float* xres = x01f + z * ZS;
  const float* g1 = g1_l + z * 1024;
  const float* bt1 = bt1_l + z * 1024;
  float* x1f = x1f2 + z * ZS;
  unsigned short* x1b = x1b2 + z * ZS;

  int wave = threadIdx.x >> 6, lane = threadIdx.x & 63;
  int n = blockIdx.x * 4 + wave;
  int l32 = lane & 31;
  int par = lane >> 5;         // edge parity
  int hch = l32 >> 3;          // head of my channel block
  int c0 = l32 * 8;            // my 8 channels
  int beg = rowptr[n], end = rowptr[n + 1];
  float4 adv = *(const float4*)&a_d[n * 4];
  const float NI = -__builtin_inff();
  float4 m4 = {NI, NI, NI, NI};
  float acc[8] = {};
  float den = 0.f;

  for (int base = beg; base < end; base += 64) {
    int cnt = min(64, end - base);
    // --- score phase: lane = edge slot ---
    float4 ev = {NI, NI, NI, NI};
    if (lane < cnt) {
      int s = csrc[base + lane];
      ssrc[wave][lane] = s;
      float4 as = *(const float4*)&a_s[s * 4];
      float e0 = as.x + adv.x; ev.x = e0 > 0.f ? e0 : 0.2f * e0;
      float e1 = as.y + adv.y; ev.y = e1 > 0.f ? e1 : 0.2f * e1;
      float e2 = as.z + adv.z; ev.z = e2 > 0.f ? e2 : 0.2f * e2;
      float e3 = as.w + adv.w; ev.w = e3 > 0.f ? e3 : 0.2f * e3;
    }
    // per-head chunk max across 64 lanes
    float4 mv = ev;
#pragma unroll
    for (int off = 32; off; off >>= 1) {
      mv.x = fmaxf(mv.x, __shfl_xor(mv.x, off));
      mv.y = fmaxf(mv.y, __shfl_xor(mv.y, off));
      mv.z = fmaxf(mv.z, __shfl_xor(mv.z, off));
      mv.w = fmaxf(mv.w, __shfl_xor(mv.w, off));
    }
    float4 m4n;
    m4n.x = fmaxf(m4.x, mv.x); m4n.y = fmaxf(m4.y, mv.y);
    m4n.z = fmaxf(m4.z, mv.z); m4n.w = fmaxf(m4.w, mv.w);
    // rescale my channels (first chunk: exp(-inf)=0)
    float rm = __expf(sel4(m4, hch) - sel4(m4n, hch));
#pragma unroll
    for (int j = 0; j < 8; ++j) acc[j] *= rm;
    den *= rm;
    // edge weights -> LDS
    if (lane < cnt) {
      float* swl = &sw[wave][lane * 5];
      swl[0] = __expf(ev.x - m4n.x);
      swl[1] = __expf(ev.y - m4n.y);
      swl[2] = __expf(ev.z - m4n.z);
      swl[3] = __expf(ev.w - m4n.w);
    }
    m4 = m4n;
    __builtin_amdgcn_wave_barrier();  // same-wave LDS ops are in-order; fence the compiler
    // --- PV phase: 2 edges per iteration ---
    for (int i = par; i < cnt; i += 2) {
      float w = sw[wave][i * 5 + hch];
      int s_i = ssrc[wave][i];
      bf16x8 hv = *(const bf16x8*)(hb + (size_t)s_i * 256 + c0);
#pragma unroll
      for (int j = 0; j < 8; ++j)
        acc[j] = fmaf(bf2f((unsigned short)hv[j]), w, acc[j]);
      den += w;
    }
    __builtin_amdgcn_wave_barrier();
  }

  // combine edge parities (lane ^ 32 holds same channels, other parity)
#pragma unroll
  for (int j = 0; j < 8; ++j) acc[j] += __shfl_xor(acc[j], 32);
  den += __shfl_xor(den, 32);

  float invden = 1.f / fmaxf(den, 1e-16f);
  float outv[8];
  float s1 = 0.f, s2 = 0.f;
#pragma unroll
  for (int j = 0; j < 8; ++j) {
    float v = acc[j] * invden + bias[c0 + j] + xres[(size_t)n * 256 + c0 + j];
    outv[j] = v;
    s1 += v;
    s2 += v * v;
  }
  // LN reduce over the 32-lane half (halves hold identical data)
#pragma unroll
  for (int off = 16; off; off >>= 1) {
    s1 += __shfl_xor(s1, off);
    s2 += __shfl_xor(s2, off);
  }
  float mean = s1 * (1.f / 256.f);
  float var = s2 * (1.f / 256.f) - mean * mean;
  float rst = rsqrtf(var + 1e-5f);
  if (par == 0) {
    float4 y0, y1;
    unsigned short yb[8];
#pragma unroll
    for (int j = 0; j < 8; ++j) {
      float y = (outv[j] - mean) * rst * g1[c0 + j] + bt1[c0 + j];
      if (j < 4) ((float*)&y0)[j] = y; else ((float*)&y1)[j - 4] = y;
      yb[j] = f2bf(y);
    }
    size_t idx = (size_t)n * 256 + c0;
    *(float4*)&x1f[idx] = y0;
    *(float4*)&x1f[idx + 4] = y1;
    *(bf16x8*)&x1b[idx] = *(bf16x8*)yb;
  }
}

// ---------------- dual LN2 (both streams) + optional next-layer prep ----------------
// tf01 = x01f (FFN2 wrote pre-LN2 values there); PREP overwrites x01f/x01b for next layer.
template <int PREP>
__global__ __launch_bounds__(256) void ln2_kernel(const float* __restrict__ tf01,
                                                  const float* __restrict__ g2_l,
                                                  const float* __restrict__ bt2_l,
                                                  float* __restrict__ out_hf,
                                                  float* __restrict__ out_hs,
                                                  float* __restrict__ x01f,
                                                  unsigned short* __restrict__ x01b) {
  __shared__ float red[4][4];
  const size_t ZS = (size_t)Nn * Dm;
  int n = blockIdx.x, tid = threadIdx.x;
  int head = tid >> 6, lane = tid & 63;
  size_t idx = (size_t)n * 256 + tid;
  float v0 = tf01[idx], v1 = tf01[ZS + idx];
  float a0 = v0, b0 = v0 * v0, a1 = v1, b1 = v1 * v1;
#pragma unroll
  for (int off = 32; off; off >>= 1) {
    a0 += __shfl_xor(a0, off);
    b0 += __shfl_xor(b0, off);
    a1 += __shfl_xor(a1, off);
    b1 += __shfl_xor(b1, off);
  }
  if (lane == 0) { red[head][0] = a0; red[head][1] = b0; red[head][2] = a1; red[head][3] = b1; }
  __syncthreads();
  a0 = red[0][0] + red[1][0] + red[2][0] + red[3][0];
  b0 = red[0][1] + red[1][1] + red[2][1] + red[3][1];
  a1 = red[0][2] + red[1][2] + red[2][2] + red[3][2];
  b1 = red[0][3] + red[1][3] + red[2][3] + red[3][3];
  float m0 = a0 * (1.f / 256.f), m1 = a1 * (1.f / 256.f);
  float r0 = rsqrtf(b0 * (1.f / 256.f) - m0 * m0 + 1e-5f);
  float r1 = rsqrtf(b1 * (1.f / 256.f) - m1 * m1 + 1e-5f);
  float y0 = (v0 - m0) * r0 * g2_l[tid] + bt2_l[tid];
  float y1 = (v1 - m1) * r1 * g2_l[1024 + tid] + bt2_l[1024 + tid];
  out_hf[idx] = y0;
  out_hs[idx] = y1;
  if (PREP) {
    float s = y0 + y1;
    x01f[idx] = s;      x01b[idx] = f2bf(s);
    x01f[ZS + idx] = y1; x01b[ZS + idx] = f2bf(y1);
  }
}

extern "C" void kernel_launch(void* const* d_in, const int* in_sizes, int n_in,
                              void* d_out, int out_size, void* d_ws, size_t ws_size,
                              hipStream_t stream) {
  const float* hf_in = (const float*)d_in[0];
  const float* hs_in = (const float*)d_in[1];
  const int* ei = (const int*)d_in[2];
  const int E = in_sizes[2] / 2;
  const float* Wgat = (const float*)d_in[3];
  const float* att_src = (const float*)d_in[4];
  const float* att_dst = (const float*)d_in[5];
  const float* bias_gat = (const float*)d_in[6];
  const float* W1 = (const float*)d_in[7];
  const float* b1 = (const float*)d_in[8];
  const float* W2 = (const float*)d_in[9];
  const float* b2 = (const float*)d_in[10];
  const float* g1 = (const float*)d_in[11];
  const float* bt1 = (const float*)d_in[12];
  const float* g2 = (const float*)d_in[13];
  const float* bt2 = (const float*)d_in[14];
  const int* src = ei;
  const int* dst = ei + E;
  const size_t ZS = (size_t)Nn * Dm;

  // ---- carve workspace ----
  char* wsp = (char*)d_ws;
  size_t off = 0;
  auto carve = [&](size_t bytes) -> void* {
    void* p = wsp + off;
    off += (bytes + 255) & ~(size_t)255;
    return p;
  };
  unsigned short* Wgt  = (unsigned short*)carve((size_t)8 * 256 * 256 * 2);
  unsigned short* W1t  = (unsigned short*)carve((size_t)8 * 256 * 1024 * 2);
  unsigned short* W2t  = (unsigned short*)carve((size_t)8 * 1024 * 256 * 2);
  int* cnt      = (int*)carve((size_t)Nn * 4);
  int* rowptr   = (int*)carve((size_t)(Nn + 1) * 4);
  int* cursor   = (int*)carve((size_t)Nn * 4);
  int* part     = (int*)carve((size_t)Nn * 4);
  int* bsum     = (int*)carve((size_t)64 * 4);
  int* bbase    = (int*)carve((size_t)64 * 4);
  int* csrc     = (int*)carve((size_t)E * 4);
  float* x01f   = (float*)carve(2 * ZS * 4);            // [z]: GEMM-in resid / FFN2-out (pre-LN2)
  unsigned short* x01b = (unsigned short*)carve(2 * ZS * 2);  // [z]: GEMM-in bf16
  unsigned short* hbuf2 = (unsigned short*)carve(2 * ZS * 2); // [z]: proj out bf16
  float* a_s2   = (float*)carve((size_t)2 * Nn * 4 * 4);
  float* a_d2   = (float*)carve((size_t)2 * Nn * 4 * 4);
  float* x1f2   = (float*)carve(2 * ZS * 4);            // [z]: LN1 out f32
  unsigned short* x1b2 = (unsigned short*)carve(2 * ZS * 2);  // [z]: LN1 out bf16
  unsigned short* f_b = (unsigned short*)carve((size_t)Nn * Ff * 2);
  if (off > ws_size) return;  // workspace too small — fail visibly

  // ---- once per call: weights + CSR ----
  wconv_kernel<<<1024, 256, 0, stream>>>(Wgat, Wgt, 8, 256, 256);
  wconv_kernel<<<1024, 256, 0, stream>>>(W1, W1t, 8, 256, 1024);
  wconv_kernel<<<1024, 256, 0, stream>>>(W2, W2t, 8, 1024, 256);
  hipMemsetAsync(cnt, 0, (size_t)Nn * 4, stream);
  count_kernel<<<1024, 256, 0, stream>>>(dst, E, cnt);
  scan1_kernel<<<64, 256, 0, stream>>>(cnt, part, bsum);
  scan2_kernel<<<1, 64, 0, stream>>>(bsum, bbase, rowptr);
  scan3_kernel<<<64, 256, 0, stream>>>(part, bbase, rowptr, cursor);
  fill_kernel<<<1024, 256, 0, stream>>>(src, dst, E, cursor, csrc);

  float* out_hf = (float*)d_out;
  float* out_hs = out_hf + ZS;

  prep_kernel<<<2048, 256, 0, stream>>>(hf_in, hs_in, x01f, x01b, Nn * Dm);

  for (int l = 0; l < 4; ++l) {
    // proj (both streams) + fused scores
    proj_kernel<<<dim3(128, 4, 2), 256, 0, stream>>>(
        x01b, Wgt + (size_t)l * 65536, hbuf2,
        att_src + l * 256, att_dst + l * 256, a_s2, a_d2);
    // segment softmax + aggregate + bias + residual + LN1 (both streams)
    agg_kernel<<<dim3(Nn / 4, 2), 256, 0, stream>>>(
        hbuf2, a_s2, a_d2, rowptr, csrc,
        bias_gat + l * 256, x01f, g1 + l * 256, bt1 + l * 256, x1f2, x1b2);
    // FFN per stream (shared f_b buffer)
    for (int s = 0; s < 2; ++s) {
      int b = s * 4 + l;
      gemm_kernel<<<dim3(128, 8), 256, 0, stream>>>(
          x1b2 + s * ZS, W1t + (size_t)b * 256 * 1024, f_b,
          b1 + (size_t)b * 1024, Nn, 256, 1024);
      gemm64_kernel<<<dim3(128, 4), 256, 0, stream>>>(
          f_b, W2t + (size_t)b * 1024 * 256, x01f + s * ZS,
          b2 + (size_t)b * 256, x1f2 + s * ZS, Nn, 1024, 256);
    }
    // dual LN2 -> states (+ next-layer prep for l<3)
    if (l < 3) {
      ln2_kernel<1><<<Nn, 256, 0, stream>>>(x01f, g2 + l * 256, bt2 + l * 256,
                                            out_hf, out_hs, x01f, x01b);
    } else {
      ln2_kernel<0><<<Nn, 256, 0, stream>>>(x01f, g2 + l * 256, bt2 + l * 256,
                                            out_hf, out_hs, x01f, x01b);
    }
  }
}

// Round 6
// 769.184 us; speedup vs baseline: 1.8446x; 1.0929x over previous
//
#include <hip/hip_runtime.h>

#define Nn 16384
#define Dm 256
#define Ff 1024

typedef __attribute__((ext_vector_type(8))) short bf16x8;
typedef __attribute__((ext_vector_type(4))) float f32x4;

typedef const __attribute__((address_space(1))) unsigned int glb_u32;
typedef __attribute__((address_space(3))) unsigned int lds_u32;

__device__ __forceinline__ void async_copy16(const void* g, void* l) {
  __builtin_amdgcn_global_load_lds((glb_u32*)g, (lds_u32*)l, 16, 0, 0);
}

__device__ __forceinline__ unsigned short f2bf(float f) {
  union { float f; unsigned u; } v; v.f = f;
  return (unsigned short)((v.u + 0x7FFFu + ((v.u >> 16) & 1u)) >> 16);
}

__device__ __forceinline__ float bf2f(unsigned short u) {
  union { unsigned u; float f; } v; v.u = ((unsigned)u) << 16;
  return v.f;
}

__device__ __forceinline__ float sel4(float4 v, int h) {
  float r = v.x;
  r = (h == 1) ? v.y : r;
  r = (h == 2) ? v.z : r;
  r = (h == 3) ? v.w : r;
  return r;
}

// ---------------- tiled weight convert+transpose: wt[b][j][k] = bf16(w[b][k][j]) ----------------
// 64x64 tiles via LDS; coalesced read + coalesced write.
__global__ __launch_bounds__(256) void wconvt_kernel(const float* __restrict__ w,
                                                     unsigned short* __restrict__ wt,
                                                     int K, int J) {
  __shared__ unsigned short t[64][65];
  int b = blockIdx.z;
  int j0 = blockIdx.x * 64, k0 = blockIdx.y * 64;
  int tj = threadIdx.x & 63, q = threadIdx.x >> 6;  // 4 rows per pass
  const float* wb = w + (size_t)b * K * J;
#pragma unroll
  for (int r = 0; r < 16; ++r) {
    int k = r * 4 + q;
    t[k][tj] = f2bf(wb[(size_t)(k0 + k) * J + j0 + tj]);
  }
  __syncthreads();
  unsigned short* wtb = wt + (size_t)b * K * J;
#pragma unroll
  for (int r = 0; r < 16; ++r) {
    int j = r * 4 + q;
    wtb[(size_t)(j0 + j) * K + k0 + tj] = t[tj][j];
  }
}

// ---------------- CSR build ----------------
__global__ void count_kernel(const int* __restrict__ dst, int E, int* __restrict__ cnt) {
  for (int e = blockIdx.x * blockDim.x + threadIdx.x; e < E; e += gridDim.x * blockDim.x)
    atomicAdd(&cnt[dst[e]], 1);
}

__global__ __launch_bounds__(256) void scan1_kernel(const int* __restrict__ cnt,
                                                    int* __restrict__ part,
                                                    int* __restrict__ bsum) {
  __shared__ int sd[256];
  int b = blockIdx.x, tid = threadIdx.x;
  int v = cnt[b * 256 + tid];
  sd[tid] = v;
  __syncthreads();
  for (int offt = 1; offt < 256; offt <<= 1) {
    int t = (tid >= offt) ? sd[tid - offt] : 0;
    __syncthreads();
    sd[tid] += t;
    __syncthreads();
  }
  part[b * 256 + tid] = sd[tid] - v;  // exclusive
  if (tid == 255) bsum[b] = sd[255];
}

__global__ __launch_bounds__(64) void scan2_kernel(const int* __restrict__ bsum,
                                                   int* __restrict__ bbase,
                                                   int* __restrict__ rowptr) {
  __shared__ int sd[64];
  int tid = threadIdx.x;
  int v = bsum[tid];
  sd[tid] = v;
  __syncthreads();
  for (int offt = 1; offt < 64; offt <<= 1) {
    int t = (tid >= offt) ? sd[tid - offt] : 0;
    __syncthreads();
    sd[tid] += t;
    __syncthreads();
  }
  bbase[tid] = sd[tid] - v;
  if (tid == 63) rowptr[Nn] = sd[63];
}

__global__ __launch_bounds__(256) void scan3_kernel(const int* __restrict__ part,
                                                    const int* __restrict__ bbase,
                                                    int* __restrict__ rowptr,
                                                    int* __restrict__ cursor) {
  int b = blockIdx.x, tid = threadIdx.x;
  int v = part[b * 256 + tid] + bbase[b];
  rowptr[b * 256 + tid] = v;
  cursor[b * 256 + tid] = v;
}

__global__ void fill_kernel(const int* __restrict__ src, const int* __restrict__ dst, int E,
                            int* __restrict__ cursor, int* __restrict__ csrc) {
  for (int e = blockIdx.x * blockDim.x + threadIdx.x; e < E; e += gridDim.x * blockDim.x) {
    int pos = atomicAdd(&cursor[dst[e]], 1);
    csrc[pos] = src[e];
  }
}

// ---------------- initial input prep (layer 0): x01f[0]=hf+hs, x01f[1]=hs ----------------
__global__ void prep_kernel(const float* __restrict__ hf, const float* __restrict__ hs,
                            float* __restrict__ x01f, unsigned short* __restrict__ x01b,
                            int total) {
  const size_t ZS = (size_t)Nn * Dm;
  for (int i = blockIdx.x * blockDim.x + threadIdx.x; i < total; i += gridDim.x * blockDim.x) {
    float a = hf[i], b = hs[i];
    float s = a + b;
    x01f[i] = s; x01b[i] = f2bf(s);
    x01f[ZS + i] = b; x01b[ZS + i] = f2bf(b);
  }
}

// ---------------- proj GEMM (both streams, z=blockIdx.z) + fused attention scores ----------------
__global__ __launch_bounds__(256, 2) void proj_kernel(
    const unsigned short* __restrict__ xib, const unsigned short* __restrict__ Wgt_l,
    unsigned short* __restrict__ hbuf2, const float* __restrict__ asr_l,
    const float* __restrict__ ads_l, float* __restrict__ a_s2, float* __restrict__ a_d2) {
  __shared__ __align__(16) unsigned short sA[128 * 32];
  __shared__ __align__(16) unsigned short sB[64 * 32];
  const int K = 256;
  const size_t ZS = (size_t)Nn * Dm;
  int tid = threadIdx.x;
  int wave = tid >> 6, lane = tid & 63;
  int l16 = lane & 15, lhi = lane >> 4;
  int brow = blockIdx.x, bcol = blockIdx.y, z = blockIdx.z;
  int wm = wave >> 1, wn = wave & 1;  // wave tile 64x32

  const unsigned short* Ab = xib + z * ZS + (size_t)brow * 128 * K;
  const unsigned short* Bb = Wgt_l + (size_t)z * 4 * 65536 + (size_t)bcol * 64 * K;

  int ldrow = lane >> 2;
  int ldk = (lane & 3) * 8;

  f32x4 acc[4][2] = {};

  for (int k0 = 0; k0 < K; k0 += 32) {
    int r0 = wave * 16;
    async_copy16(Ab + (size_t)(r0 + ldrow) * K + k0 + ldk, &sA[r0 * 32]);
    async_copy16(Ab + (size_t)(r0 + 64 + ldrow) * K + k0 + ldk, &sA[(r0 + 64) * 32]);
    async_copy16(Bb + (size_t)(r0 + ldrow) * K + k0 + ldk, &sB[r0 * 32]);
    __syncthreads();
    bf16x8 af[4], bfr[2];
#pragma unroll
    for (int mi = 0; mi < 4; ++mi)
      af[mi] = *(const bf16x8*)&sA[(wm * 64 + mi * 16 + l16) * 32 + lhi * 8];
#pragma unroll
    for (int ni = 0; ni < 2; ++ni)
      bfr[ni] = *(const bf16x8*)&sB[(wn * 32 + ni * 16 + l16) * 32 + lhi * 8];
#pragma unroll
    for (int mi = 0; mi < 4; ++mi)
#pragma unroll
      for (int ni = 0; ni < 2; ++ni)
        acc[mi][ni] = __builtin_amdgcn_mfma_f32_16x16x32_bf16(af[mi], bfr[ni], acc[mi][ni], 0, 0, 0);
    __syncthreads();
  }

  // ---- epilogue: C store (bf16) + per-row attention-score partials ----
  unsigned short* hb = hbuf2 + z * ZS;
  const float* asr_p = asr_l + z * 1024 + bcol * 64;
  const float* ads_p = ads_l + z * 1024 + bcol * 64;
  float as0 = asr_p[wn * 32 + l16],      ad0 = ads_p[wn * 32 + l16];
  float as1 = asr_p[wn * 32 + 16 + l16], ad1 = ads_p[wn * 32 + 16 + l16];
  float* sredS = (float*)sA;        // [wm][wn][64] = 256 floats
  float* sredD = (float*)sA + 256;  // (sA dead after K loop)

#pragma unroll
  for (int mi = 0; mi < 4; ++mi) {
#pragma unroll
    for (int j = 0; j < 4; ++j) {
      int r = brow * 128 + wm * 64 + mi * 16 + lhi * 4 + j;
      float v0 = acc[mi][0][j], v1 = acc[mi][1][j];
      hb[(size_t)r * 256 + bcol * 64 + wn * 32 + l16] = f2bf(v0);
      hb[(size_t)r * 256 + bcol * 64 + wn * 32 + 16 + l16] = f2bf(v1);
      float ps = v0 * as0 + v1 * as1;
      float pd = v0 * ad0 + v1 * ad1;
#pragma unroll
      for (int off = 1; off < 16; off <<= 1) {
        ps += __shfl_xor(ps, off);
        pd += __shfl_xor(pd, off);
      }
      if (l16 == 0) {
        int rl = mi * 16 + lhi * 4 + j;  // row within wave tile [0,64)
        sredS[wm * 128 + wn * 64 + rl] = ps;
        sredD[wm * 128 + wn * 64 + rl] = pd;
      }
    }
  }
  __syncthreads();
  if (tid < 128) {
    int w = tid >> 6, rl = tid & 63;
    float s = sredS[w * 128 + rl] + sredS[w * 128 + 64 + rl];
    float d = sredD[w * 128 + rl] + sredD[w * 128 + 64 + rl];
    int row = brow * 128 + tid;
    a_s2[(size_t)z * Nn * 4 + row * 4 + bcol] = s;
    a_d2[(size_t)z * Nn * 4 + row * 4 + bcol] = d;
  }
}

// ---------------- FFN1: f = relu(x1 @ W1 + b1), BK=64, BM=BN=128, z=stream ----------------
__global__ __launch_bounds__(256, 2) void ffn1_kernel(
    const unsigned short* __restrict__ A2, const unsigned short* __restrict__ Bt_l,
    unsigned short* __restrict__ out2, const float* __restrict__ b1_l) {
  const int K = 256, Ncol = Ff;
  const size_t ZS = (size_t)Nn * Dm;
  __shared__ __align__(16) unsigned short sA[128 * 64];
  __shared__ __align__(16) unsigned short sB[128 * 64];
  int tid = threadIdx.x, wave = tid >> 6, lane = tid & 63;
  int l16 = lane & 15, lhi = lane >> 4;
  int brow = blockIdx.x, bcol = blockIdx.y, z = blockIdx.z;
  int wm = wave >> 1, wn = wave & 1;  // wave tile 64x64

  const unsigned short* Ab = A2 + z * ZS + (size_t)brow * 128 * K;
  const unsigned short* Bb = Bt_l + (size_t)z * 4 * Ff * 256 + (size_t)bcol * 128 * K;
  int lrow = lane >> 3, lk = (lane & 7) * 8;

  f32x4 acc[4][4] = {};

  for (int k0 = 0; k0 < K; k0 += 64) {
#pragma unroll
    for (int r = 0; r < 4; ++r) {
      int rb = r * 32 + wave * 8;
      async_copy16(Ab + (size_t)(rb + lrow) * K + k0 + lk, &sA[rb * 64]);
      async_copy16(Bb + (size_t)(rb + lrow) * K + k0 + lk, &sB[rb * 64]);
    }
    __syncthreads();
#pragma unroll
    for (int kk = 0; kk < 2; ++kk) {
      bf16x8 af[4], bfr[4];
#pragma unroll
      for (int mi = 0; mi < 4; ++mi)
        af[mi] = *(const bf16x8*)&sA[(wm * 64 + mi * 16 + l16) * 64 + kk * 32 + lhi * 8];
#pragma unroll
      for (int ni = 0; ni < 4; ++ni)
        bfr[ni] = *(const bf16x8*)&sB[(wn * 64 + ni * 16 + l16) * 64 + kk * 32 + lhi * 8];
#pragma unroll
      for (int mi = 0; mi < 4; ++mi)
#pragma unroll
        for (int ni = 0; ni < 4; ++ni)
          acc[mi][ni] = __builtin_amdgcn_mfma_f32_16x16x32_bf16(af[mi], bfr[ni], acc[mi][ni], 0, 0, 0);
    }
    __syncthreads();
  }

  unsigned short* outB = out2 + (size_t)z * Nn * Ff;
  const float* bias = b1_l + z * 4096;
#pragma unroll
  for (int mi = 0; mi < 4; ++mi) {
#pragma unroll
    for (int ni = 0; ni < 4; ++ni) {
#pragma unroll
      for (int j = 0; j < 4; ++j) {
        int r = brow * 128 + wm * 64 + mi * 16 + lhi * 4 + j;
        int c = bcol * 128 + wn * 64 + ni * 16 + l16;
        float v = acc[mi][ni][j] + bias[c];
        v = v > 0.f ? v : 0.f;
        outB[(size_t)r * Ncol + c] = f2bf(v);
      }
    }
  }
}

// ---------------- FFN2: t = f @ W2 + b2 + x1, BK=64, BM=128 BN=64, z=stream ----------------
__global__ __launch_bounds__(256, 2) void ffn2_kernel(
    const unsigned short* __restrict__ A2, const unsigned short* __restrict__ Bt_l,
    float* __restrict__ out2, const float* __restrict__ b2_l,
    const float* __restrict__ resid2) {
  const int K = Ff, Ncol = 256;
  const size_t ZS = (size_t)Nn * Dm;
  __shared__ __align__(16) unsigned short sA[128 * 64];
  __shared__ __align__(16) unsigned short sB[64 * 64];
  int tid = threadIdx.x, wave = tid >> 6, lane = tid & 63;
  int l16 = lane & 15, lhi = lane >> 4;
  int brow = blockIdx.x, bcol = blockIdx.y, z = blockIdx.z;
  int wm = wave >> 1, wn = wave & 1;  // wave tile 64x32

  const unsigned short* Ab = A2 + (size_t)z * Nn * Ff + (size_t)brow * 128 * K;
  const unsigned short* Bb = Bt_l + (size_t)z * 4 * Ff * 256 + (size_t)bcol * 64 * K;
  int lrow = lane >> 3, lk = (lane & 7) * 8;

  f32x4 acc[4][2] = {};

  for (int k0 = 0; k0 < K; k0 += 64) {
#pragma unroll
    for (int r = 0; r < 4; ++r) {
      int rb = r * 32 + wave * 8;
      async_copy16(Ab + (size_t)(rb + lrow) * K + k0 + lk, &sA[rb * 64]);
      if (r < 2)
        async_copy16(Bb + (size_t)(rb + lrow) * K + k0 + lk, &sB[rb * 64]);
    }
    __syncthreads();
#pragma unroll
    for (int kk = 0; kk < 2; ++kk) {
      bf16x8 af[4], bfr[2];
#pragma unroll
      for (int mi = 0; mi < 4; ++mi)
        af[mi] = *(const bf16x8*)&sA[(wm * 64 + mi * 16 + l16) * 64 + kk * 32 + lhi * 8];
#pragma unroll
      for (int ni = 0; ni < 2; ++ni)
        bfr[ni] = *(const bf16x8*)&sB[(wn * 32 + ni * 16 + l16) * 64 + kk * 32 + lhi * 8];
#pragma unroll
      for (int mi = 0; mi < 4; ++mi)
#pragma unroll
        for (int ni = 0; ni < 2; ++ni)
          acc[mi][ni] = __builtin_amdgcn_mfma_f32_16x16x32_bf16(af[mi], bfr[ni], acc[mi][ni], 0, 0, 0);
    }
    __syncthreads();
  }

  float* outF = out2 + z * ZS;
  const float* bias = b2_l + z * 1024;
  const float* resid = resid2 + z * ZS;
#pragma unroll
  for (int mi = 0; mi < 4; ++mi) {
#pragma unroll
    for (int ni = 0; ni < 2; ++ni) {
#pragma unroll
      for (int j = 0; j < 4; ++j) {
        int r = brow * 128 + wm * 64 + mi * 16 + lhi * 4 + j;
        int c = bcol * 64 + wn * 32 + ni * 16 + l16;
        float v = acc[mi][ni][j] + bias[c] + resid[(size_t)r * Ncol + c];
        outF[(size_t)r * Ncol + c] = v;
      }
    }
  }
}

// ---------------- wave-per-node fused softmax + aggregation + bias + residual + LN1 ----------------
// grid (Nn/4, 2): y = stream. 4 waves/block, node = blockIdx.x*4 + wave. Barrier-free.
__global__ __launch_bounds__(256) void agg_kernel(
    const unsigned short* __restrict__ hbuf2, const float* __restrict__ a_s2,
    const float* __restrict__ a_d2,
    const int* __restrict__ rowptr, const int* __restrict__ csrc,
    const float* __restrict__ bias_l, const float* __restrict__ x01f,
    const float* __restrict__ g1_l, const float* __restrict__ bt1_l,
    float* __restrict__ x1f2, unsigned short* __restrict__ x1b2) {
  __shared__ float sw[4][320];  // [wave][slot*5 + head]  (stride 5: conflict-free)
  __shared__ int ssrc[4][64];
  const size_t ZS = (size_t)Nn * Dm;
  int z = blockIdx.y;
  const unsigned short* hb = hbuf2 + z * ZS;
  const float* a_s = a_s2 + (size_t)z * Nn * 4;
  const float* a_d = a_d2 + (size_t)z * Nn * 4;
  const float* bias = bias_l + z * 1024;
  const float* xres = x01f + z * ZS;
  const float* g1 = g1_l + z * 1024;
  const float* bt1 = bt1_l + z * 1024;
  float* x1f = x1f2 + z * ZS;
  unsigned short* x1b = x1b2 + z * ZS;

  int wave = threadIdx.x >> 6, lane = threadIdx.x & 63;
  int n = blockIdx.x * 4 + wave;
  int l32 = lane & 31;
  int par = lane >> 5;         // edge parity
  int hch = l32 >> 3;          // head of my channel block
  int c0 = l32 * 8;            // my 8 channels
  int beg = rowptr[n], end = rowptr[n + 1];
  float4 adv = *(const float4*)&a_d[n * 4];
  const float NI = -__builtin_inff();
  float4 m4 = {NI, NI, NI, NI};
  float acc[8] = {};
  float den = 0.f;

  for (int base = beg; base < end; base += 64) {
    int cnt = min(64, end - base);
    // --- score phase: lane = edge slot ---
    float4 ev = {NI, NI, NI, NI};
    if (lane < cnt) {
      int s = csrc[base + lane];
      ssrc[wave][lane] = s;
      float4 as = *(const float4*)&a_s[s * 4];
      float e0 = as.x + adv.x; ev.x = e0 > 0.f ? e0 : 0.2f * e0;
      float e1 = as.y + adv.y; ev.y = e1 > 0.f ? e1 : 0.2f * e1;
      float e2 = as.z + adv.z; ev.z = e2 > 0.f ? e2 : 0.2f * e2;
      float e3 = as.w + adv.w; ev.w = e3 > 0.f ? e3 : 0.2f * e3;
    }
    // per-head chunk max across 64 lanes
    float4 mv = ev;
#pragma unroll
    for (int off = 32; off; off >>= 1) {
      mv.x = fmaxf(mv.x, __shfl_xor(mv.x, off));
      mv.y = fmaxf(mv.y, __shfl_xor(mv.y, off));
      mv.z = fmaxf(mv.z, __shfl_xor(mv.z, off));
      mv.w = fmaxf(mv.w, __shfl_xor(mv.w, off));
    }
    float4 m4n;
    m4n.x = fmaxf(m4.x, mv.x); m4n.y = fmaxf(m4.y, mv.y);
    m4n.z = fmaxf(m4.z, mv.z); m4n.w = fmaxf(m4.w, mv.w);
    // rescale my channels (first chunk: exp(-inf)=0)
    float rm = __expf(sel4(m4, hch) - sel4(m4n, hch));
#pragma unroll
    for (int j = 0; j < 8; ++j) acc[j] *= rm;
    den *= rm;
    // edge weights -> LDS
    if (lane < cnt) {
      float* swl = &sw[wave][lane * 5];
      swl[0] = __expf(ev.x - m4n.x);
      swl[1] = __expf(ev.y - m4n.y);
      swl[2] = __expf(ev.z - m4n.z);
      swl[3] = __expf(ev.w - m4n.w);
    }
    m4 = m4n;
    __builtin_amdgcn_wave_barrier();  // same-wave LDS ops are in-order; fence the compiler
    // --- PV phase: unrolled x2, 2 independent gathers in flight ---
    int i = par;
    for (; i + 2 < cnt; i += 4) {
      int s0 = ssrc[wave][i], s1 = ssrc[wave][i + 2];
      float w0 = sw[wave][i * 5 + hch], w1 = sw[wave][(i + 2) * 5 + hch];
      bf16x8 h0 = *(const bf16x8*)(hb + (size_t)s0 * 256 + c0);
      bf16x8 h1 = *(const bf16x8*)(hb + (size_t)s1 * 256 + c0);
#pragma unroll
      for (int j = 0; j < 8; ++j)
        acc[j] = fmaf(bf2f((unsigned short)h0[j]), w0, acc[j]);
#pragma unroll
      for (int j = 0; j < 8; ++j)
        acc[j] = fmaf(bf2f((unsigned short)h1[j]), w1, acc[j]);
      den += w0 + w1;
    }
    for (; i < cnt; i += 2) {
      float w = sw[wave][i * 5 + hch];
      int s_i = ssrc[wave][i];
      bf16x8 hv = *(const bf16x8*)(hb + (size_t)s_i * 256 + c0);
#pragma unroll
      for (int j = 0; j < 8; ++j)
        acc[j] = fmaf(bf2f((unsigned short)hv[j]), w, acc[j]);
      den += w;
    }
    __builtin_amdgcn_wave_barrier();
  }

  // combine edge parities (lane ^ 32 holds same channels, other parity)
#pragma unroll
  for (int j = 0; j < 8; ++j) acc[j] += __shfl_xor(acc[j], 32);
  den += __shfl_xor(den, 32);

  float invden = 1.f / fmaxf(den, 1e-16f);
  float outv[8];
  float s1 = 0.f, s2 = 0.f;
#pragma unroll
  for (int j = 0; j < 8; ++j) {
    float v = acc[j] * invden + bias[c0 + j] + xres[(size_t)n * 256 + c0 + j];
    outv[j] = v;
    s1 += v;
    s2 += v * v;
  }
  // LN reduce over the 32-lane half (halves hold identical data)
#pragma unroll
  for (int off = 16; off; off >>= 1) {
    s1 += __shfl_xor(s1, off);
    s2 += __shfl_xor(s2, off);
  }
  float mean = s1 * (1.f / 256.f);
  float var = s2 * (1.f / 256.f) - mean * mean;
  float rst = rsqrtf(var + 1e-5f);
  if (par == 0) {
    float4 y0, y1;
    unsigned short yb[8];
#pragma unroll
    for (int j = 0; j < 8; ++j) {
      float y = (outv[j] - mean) * rst * g1[c0 + j] + bt1[c0 + j];
      if (j < 4) ((float*)&y0)[j] = y; else ((float*)&y1)[j - 4] = y;
      yb[j] = f2bf(y);
    }
    size_t idx = (size_t)n * 256 + c0;
    *(float4*)&x1f[idx] = y0;
    *(float4*)&x1f[idx + 4] = y1;
    *(bf16x8*)&x1b[idx] = *(bf16x8*)yb;
  }
}

// ---------------- dual LN2 (both streams) + optional next-layer prep ----------------
template <int PREP>
__global__ __launch_bounds__(256) void ln2_kernel(const float* __restrict__ tf01,
                                                  const float* __restrict__ g2_l,
                                                  const float* __restrict__ bt2_l,
                                                  float* __restrict__ out_hf,
                                                  float* __restrict__ out_hs,
                                                  float* __restrict__ x01f,
                                                  unsigned short* __restrict__ x01b) {
  __shared__ float red[4][4];
  const size_t ZS = (size_t)Nn * Dm;
  int n = blockIdx.x, tid = threadIdx.x;
  int head = tid >> 6, lane = tid & 63;
  size_t idx = (size_t)n * 256 + tid;
  float v0 = tf01[idx], v1 = tf01[ZS + idx];
  float a0 = v0, b0 = v0 * v0, a1 = v1, b1 = v1 * v1;
#pragma unroll
  for (int off = 32; off; off >>= 1) {
    a0 += __shfl_xor(a0, off);
    b0 += __shfl_xor(b0, off);
    a1 += __shfl_xor(a1, off);
    b1 += __shfl_xor(b1, off);
  }
  if (lane == 0) { red[head][0] = a0; red[head][1] = b0; red[head][2] = a1; red[head][3] = b1; }
  __syncthreads();
  a0 = red[0][0] + red[1][0] + red[2][0] + red[3][0];
  b0 = red[0][1] + red[1][1] + red[2][1] + red[3][1];
  a1 = red[0][2] + red[1][2] + red[2][2] + red[3][2];
  b1 = red[0][3] + red[1][3] + red[2][3] + red[3][3];
  float m0 = a0 * (1.f / 256.f), m1 = a1 * (1.f / 256.f);
  float r0 = rsqrtf(b0 * (1.f / 256.f) - m0 * m0 + 1e-5f);
  float r1 = rsqrtf(b1 * (1.f / 256.f) - m1 * m1 + 1e-5f);
  float y0 = (v0 - m0) * r0 * g2_l[tid] + bt2_l[tid];
  float y1 = (v1 - m1) * r1 * g2_l[1024 + tid] + bt2_l[1024 + tid];
  out_hf[idx] = y0;
  out_hs[idx] = y1;
  if (PREP) {
    float s = y0 + y1;
    x01f[idx] = s;      x01b[idx] = f2bf(s);
    x01f[ZS + idx] = y1; x01b[ZS + idx] = f2bf(y1);
  }
}

extern "C" void kernel_launch(void* const* d_in, const int* in_sizes, int n_in,
                              void* d_out, int out_size, void* d_ws, size_t ws_size,
                              hipStream_t stream) {
  const float* hf_in = (const float*)d_in[0];
  const float* hs_in = (const float*)d_in[1];
  const int* ei = (const int*)d_in[2];
  const int E = in_sizes[2] / 2;
  const float* Wgat = (const float*)d_in[3];
  const float* att_src = (const float*)d_in[4];
  const float* att_dst = (const float*)d_in[5];
  const float* bias_gat = (const float*)d_in[6];
  const float* W1 = (const float*)d_in[7];
  const float* b1 = (const float*)d_in[8];
  const float* W2 = (const float*)d_in[9];
  const float* b2 = (const float*)d_in[10];
  const float* g1 = (const float*)d_in[11];
  const float* bt1 = (const float*)d_in[12];
  const float* g2 = (const float*)d_in[13];
  const float* bt2 = (const float*)d_in[14];
  const int* src = ei;
  const int* dst = ei + E;
  const size_t ZS = (size_t)Nn * Dm;

  // ---- carve workspace ----
  char* wsp = (char*)d_ws;
  size_t off = 0;
  auto carve = [&](size_t bytes) -> void* {
    void* p = wsp + off;
    off += (bytes + 255) & ~(size_t)255;
    return p;
  };
  unsigned short* Wgt  = (unsigned short*)carve((size_t)8 * 256 * 256 * 2);
  unsigned short* W1t  = (unsigned short*)carve((size_t)8 * 256 * 1024 * 2);
  unsigned short* W2t  = (unsigned short*)carve((size_t)8 * 1024 * 256 * 2);
  int* cnt      = (int*)carve((size_t)Nn * 4);
  int* rowptr   = (int*)carve((size_t)(Nn + 1) * 4);
  int* cursor   = (int*)carve((size_t)Nn * 4);
  int* part     = (int*)carve((size_t)Nn * 4);
  int* bsum     = (int*)carve((size_t)64 * 4);
  int* bbase    = (int*)carve((size_t)64 * 4);
  int* csrc     = (int*)carve((size_t)E * 4);
  float* x01f   = (float*)carve(2 * ZS * 4);            // [z]: GEMM-in resid / FFN2-out (pre-LN2)
  unsigned short* x01b = (unsigned short*)carve(2 * ZS * 2);  // [z]: GEMM-in bf16
  unsigned short* hbuf2 = (unsigned short*)carve(2 * ZS * 2); // [z]: proj out bf16
  float* a_s2   = (float*)carve((size_t)2 * Nn * 4 * 4);
  float* a_d2   = (float*)carve((size_t)2 * Nn * 4 * 4);
  float* x1f2   = (float*)carve(2 * ZS * 4);            // [z]: LN1 out f32
  unsigned short* x1b2 = (unsigned short*)carve(2 * ZS * 2);  // [z]: LN1 out bf16
  unsigned short* f_b2 = (unsigned short*)carve((size_t)2 * Nn * Ff * 2);  // [z]: FFN1 out
  if (off > ws_size) return;  // workspace too small — fail visibly

  // ---- once per call: weights (tiled transpose) + CSR ----
  wconvt_kernel<<<dim3(4, 4, 8), 256, 0, stream>>>(Wgat, Wgt, 256, 256);
  wconvt_kernel<<<dim3(16, 4, 8), 256, 0, stream>>>(W1, W1t, 256, 1024);
  wconvt_kernel<<<dim3(4, 16, 8), 256, 0, stream>>>(W2, W2t, 1024, 256);
  hipMemsetAsync(cnt, 0, (size_t)Nn * 4, stream);
  count_kernel<<<1024, 256, 0, stream>>>(dst, E, cnt);
  scan1_kernel<<<64, 256, 0, stream>>>(cnt, part, bsum);
  scan2_kernel<<<1, 64, 0, stream>>>(bsum, bbase, rowptr);
  scan3_kernel<<<64, 256, 0, stream>>>(part, bbase, rowptr, cursor);
  fill_kernel<<<1024, 256, 0, stream>>>(src, dst, E, cursor, csrc);

  float* out_hf = (float*)d_out;
  float* out_hs = out_hf + ZS;

  prep_kernel<<<2048, 256, 0, stream>>>(hf_in, hs_in, x01f, x01b, Nn * Dm);

  for (int l = 0; l < 4; ++l) {
    // proj (both streams) + fused scores
    proj_kernel<<<dim3(128, 4, 2), 256, 0, stream>>>(
        x01b, Wgt + (size_t)l * 65536, hbuf2,
        att_src + l * 256, att_dst + l * 256, a_s2, a_d2);
    // segment softmax + aggregate + bias + residual + LN1 (both streams)
    agg_kernel<<<dim3(Nn / 4, 2), 256, 0, stream>>>(
        hbuf2, a_s2, a_d2, rowptr, csrc,
        bias_gat + l * 256, x01f, g1 + l * 256, bt1 + l * 256, x1f2, x1b2);
    // FFN (both streams per dispatch)
    ffn1_kernel<<<dim3(128, 8, 2), 256, 0, stream>>>(
        x1b2, W1t + (size_t)l * 256 * 1024, f_b2, b1 + l * 1024);
    ffn2_kernel<<<dim3(128, 4, 2), 256, 0, stream>>>(
        f_b2, W2t + (size_t)l * 1024 * 256, x01f, b2 + l * 256, x1f2);
    // dual LN2 -> states (+ next-layer prep for l<3)
    if (l < 3) {
      ln2_kernel<1><<<Nn, 256, 0, stream>>>(x01f, g2 + l * 256, bt2 + l * 256,
                                            out_hf, out_hs, x01f, x01b);
    } else {
      ln2_kernel<0><<<Nn, 256, 0, stream>>>(x01f, g2 + l * 256, bt2 + l * 256,
                                            out_hf, out_hs, x01f, x01b);
    }
  }
}

// Round 7
// 658.966 us; speedup vs baseline: 2.1531x; 1.1673x over previous
//
#include <hip/hip_runtime.h>

#define Nn 16384
#define Dm 256
#define Ff 1024

typedef __attribute__((ext_vector_type(8))) short bf16x8;
typedef __attribute__((ext_vector_type(4))) float f32x4;

typedef const __attribute__((address_space(1))) unsigned int glb_u32;
typedef __attribute__((address_space(3))) unsigned int lds_u32;

__device__ __forceinline__ void async_copy16(const void* g, void* l) {
  __builtin_amdgcn_global_load_lds((glb_u32*)g, (lds_u32*)l, 16, 0, 0);
}

__device__ __forceinline__ unsigned short f2bf(float f) {
  union { float f; unsigned u; } v; v.f = f;
  return (unsigned short)((v.u + 0x7FFFu + ((v.u >> 16) & 1u)) >> 16);
}

__device__ __forceinline__ float bf2f(unsigned short u) {
  union { unsigned u; float f; } v; v.u = ((unsigned)u) << 16;
  return v.f;
}

__device__ __forceinline__ float sel4(float4 v, int h) {
  float r = v.x;
  r = (h == 1) ? v.y : r;
  r = (h == 2) ? v.z : r;
  r = (h == 3) ? v.w : r;
  return r;
}

// ---------------- tiled weight convert+transpose: wt[b][j][k] = bf16(w[b][k][j]) ----------------
__global__ __launch_bounds__(256) void wconvt_kernel(const float* __restrict__ w,
                                                     unsigned short* __restrict__ wt,
                                                     int K, int J) {
  __shared__ unsigned short t[64][65];
  int b = blockIdx.z;
  int j0 = blockIdx.x * 64, k0 = blockIdx.y * 64;
  int tj = threadIdx.x & 63, q = threadIdx.x >> 6;  // 4 rows per pass
  const float* wb = w + (size_t)b * K * J;
#pragma unroll
  for (int r = 0; r < 16; ++r) {
    int k = r * 4 + q;
    t[k][tj] = f2bf(wb[(size_t)(k0 + k) * J + j0 + tj]);
  }
  __syncthreads();
  unsigned short* wtb = wt + (size_t)b * K * J;
#pragma unroll
  for (int r = 0; r < 16; ++r) {
    int j = r * 4 + q;
    wtb[(size_t)(j0 + j) * K + k0 + tj] = t[tj][j];
  }
}

// ---------------- CSR build ----------------
__global__ void count_kernel(const int* __restrict__ dst, int E, int* __restrict__ cnt) {
  for (int e = blockIdx.x * blockDim.x + threadIdx.x; e < E; e += gridDim.x * blockDim.x)
    atomicAdd(&cnt[dst[e]], 1);
}

__global__ __launch_bounds__(256) void scan1_kernel(const int* __restrict__ cnt,
                                                    int* __restrict__ part,
                                                    int* __restrict__ bsum) {
  __shared__ int sd[256];
  int b = blockIdx.x, tid = threadIdx.x;
  int v = cnt[b * 256 + tid];
  sd[tid] = v;
  __syncthreads();
  for (int offt = 1; offt < 256; offt <<= 1) {
    int t = (tid >= offt) ? sd[tid - offt] : 0;
    __syncthreads();
    sd[tid] += t;
    __syncthreads();
  }
  part[b * 256 + tid] = sd[tid] - v;  // exclusive
  if (tid == 255) bsum[b] = sd[255];
}

__global__ __launch_bounds__(64) void scan2_kernel(const int* __restrict__ bsum,
                                                   int* __restrict__ bbase,
                                                   int* __restrict__ rowptr) {
  __shared__ int sd[64];
  int tid = threadIdx.x;
  int v = bsum[tid];
  sd[tid] = v;
  __syncthreads();
  for (int offt = 1; offt < 64; offt <<= 1) {
    int t = (tid >= offt) ? sd[tid - offt] : 0;
    __syncthreads();
    sd[tid] += t;
    __syncthreads();
  }
  bbase[tid] = sd[tid] - v;
  if (tid == 63) rowptr[Nn] = sd[63];
}

__global__ __launch_bounds__(256) void scan3_kernel(const int* __restrict__ part,
                                                    const int* __restrict__ bbase,
                                                    int* __restrict__ rowptr,
                                                    int* __restrict__ cursor) {
  int b = blockIdx.x, tid = threadIdx.x;
  int v = part[b * 256 + tid] + bbase[b];
  rowptr[b * 256 + tid] = v;
  cursor[b * 256 + tid] = v;
}

__global__ void fill_kernel(const int* __restrict__ src, const int* __restrict__ dst, int E,
                            int* __restrict__ cursor, int* __restrict__ csrc) {
  for (int e = blockIdx.x * blockDim.x + threadIdx.x; e < E; e += gridDim.x * blockDim.x) {
    int pos = atomicAdd(&cursor[dst[e]], 1);
    csrc[pos] = src[e];
  }
}

// ---------------- initial input prep (layer 0): x01b[0]=bf16(hf+hs), x01b[1]=bf16(hs) ----------------
__global__ void prep_kernel(const float* __restrict__ hf, const float* __restrict__ hs,
                            unsigned short* __restrict__ x01b, int total) {
  const size_t ZS = (size_t)Nn * Dm;
  for (int i = blockIdx.x * blockDim.x + threadIdx.x; i < total; i += gridDim.x * blockDim.x) {
    float a = hf[i], b = hs[i];
    x01b[i] = f2bf(a + b);
    x01b[ZS + i] = f2bf(b);
  }
}

// ---------------- proj GEMM (both streams, z) + fused attention scores, BK=64 ----------------
__global__ __launch_bounds__(256, 2) void proj_kernel(
    const unsigned short* __restrict__ xib, const unsigned short* __restrict__ Wgt_l,
    unsigned short* __restrict__ hbuf2, const float* __restrict__ asr_l,
    const float* __restrict__ ads_l, float* __restrict__ a_s2, float* __restrict__ a_d2) {
  __shared__ __align__(16) unsigned short sA[128 * 64];
  __shared__ __align__(16) unsigned short sB[64 * 64];
  const int K = 256;
  const size_t ZS = (size_t)Nn * Dm;
  int tid = threadIdx.x;
  int wave = tid >> 6, lane = tid & 63;
  int l16 = lane & 15, lhi = lane >> 4;
  int brow = blockIdx.x, bcol = blockIdx.y, z = blockIdx.z;
  int wm = wave >> 1, wn = wave & 1;  // wave tile 64x32

  const unsigned short* Ab = xib + z * ZS + (size_t)brow * 128 * K;
  const unsigned short* Bb = Wgt_l + (size_t)z * 4 * 65536 + (size_t)bcol * 64 * K;
  int lrow = lane >> 3, lk = (lane & 7) * 8;

  f32x4 acc[4][2] = {};

  for (int k0 = 0; k0 < K; k0 += 64) {
#pragma unroll
    for (int r = 0; r < 4; ++r) {
      int rb = r * 32 + wave * 8;
      async_copy16(Ab + (size_t)(rb + lrow) * K + k0 + lk, &sA[rb * 64]);
      if (r < 2)
        async_copy16(Bb + (size_t)(rb + lrow) * K + k0 + lk, &sB[rb * 64]);
    }
    __syncthreads();
#pragma unroll
    for (int kk = 0; kk < 2; ++kk) {
      bf16x8 af[4], bfr[2];
#pragma unroll
      for (int mi = 0; mi < 4; ++mi)
        af[mi] = *(const bf16x8*)&sA[(wm * 64 + mi * 16 + l16) * 64 + kk * 32 + lhi * 8];
#pragma unroll
      for (int ni = 0; ni < 2; ++ni)
        bfr[ni] = *(const bf16x8*)&sB[(wn * 32 + ni * 16 + l16) * 64 + kk * 32 + lhi * 8];
#pragma unroll
      for (int mi = 0; mi < 4; ++mi)
#pragma unroll
        for (int ni = 0; ni < 2; ++ni)
          acc[mi][ni] = __builtin_amdgcn_mfma_f32_16x16x32_bf16(af[mi], bfr[ni], acc[mi][ni], 0, 0, 0);
    }
    __syncthreads();
  }

  // ---- epilogue: C store (bf16) + per-row attention-score partials ----
  unsigned short* hb = hbuf2 + z * ZS;
  const float* asr_p = asr_l + z * 1024 + bcol * 64;
  const float* ads_p = ads_l + z * 1024 + bcol * 64;
  float as0 = asr_p[wn * 32 + l16],      ad0 = ads_p[wn * 32 + l16];
  float as1 = asr_p[wn * 32 + 16 + l16], ad1 = ads_p[wn * 32 + 16 + l16];
  float* sredS = (float*)sA;        // [wm][wn][64] = 256 floats
  float* sredD = (float*)sA + 256;  // (sA dead after K loop)

#pragma unroll
  for (int mi = 0; mi < 4; ++mi) {
#pragma unroll
    for (int j = 0; j < 4; ++j) {
      int r = brow * 128 + wm * 64 + mi * 16 + lhi * 4 + j;
      float v0 = acc[mi][0][j], v1 = acc[mi][1][j];
      hb[(size_t)r * 256 + bcol * 64 + wn * 32 + l16] = f2bf(v0);
      hb[(size_t)r * 256 + bcol * 64 + wn * 32 + 16 + l16] = f2bf(v1);
      float ps = v0 * as0 + v1 * as1;
      float pd = v0 * ad0 + v1 * ad1;
#pragma unroll
      for (int off = 1; off < 16; off <<= 1) {
        ps += __shfl_xor(ps, off);
        pd += __shfl_xor(pd, off);
      }
      if (l16 == 0) {
        int rl = mi * 16 + lhi * 4 + j;  // row within wave tile [0,64)
        sredS[wm * 128 + wn * 64 + rl] = ps;
        sredD[wm * 128 + wn * 64 + rl] = pd;
      }
    }
  }
  __syncthreads();
  if (tid < 128) {
    int w = tid >> 6, rl = tid & 63;
    float s = sredS[w * 128 + rl] + sredS[w * 128 + 64 + rl];
    float d = sredD[w * 128 + rl] + sredD[w * 128 + 64 + rl];
    int row = brow * 128 + tid;
    a_s2[(size_t)z * Nn * 4 + row * 4 + bcol] = s;
    a_d2[(size_t)z * Nn * 4 + row * 4 + bcol] = d;
  }
}

// ---------------- FFN1: f = relu(x1 @ W1 + b1), BK=64, BM=BN=128, z=stream ----------------
__global__ __launch_bounds__(256, 2) void ffn1_kernel(
    const unsigned short* __restrict__ A2, const unsigned short* __restrict__ Bt_l,
    unsigned short* __restrict__ out2, const float* __restrict__ b1_l) {
  const int K = 256, Ncol = Ff;
  const size_t ZS = (size_t)Nn * Dm;
  __shared__ __align__(16) unsigned short sA[128 * 64];
  __shared__ __align__(16) unsigned short sB[128 * 64];
  int tid = threadIdx.x, wave = tid >> 6, lane = tid & 63;
  int l16 = lane & 15, lhi = lane >> 4;
  int brow = blockIdx.x, bcol = blockIdx.y, z = blockIdx.z;
  int wm = wave >> 1, wn = wave & 1;  // wave tile 64x64

  const unsigned short* Ab = A2 + z * ZS + (size_t)brow * 128 * K;
  const unsigned short* Bb = Bt_l + (size_t)z * 4 * Ff * 256 + (size_t)bcol * 128 * K;
  int lrow = lane >> 3, lk = (lane & 7) * 8;

  f32x4 acc[4][4] = {};

  for (int k0 = 0; k0 < K; k0 += 64) {
#pragma unroll
    for (int r = 0; r < 4; ++r) {
      int rb = r * 32 + wave * 8;
      async_copy16(Ab + (size_t)(rb + lrow) * K + k0 + lk, &sA[rb * 64]);
      async_copy16(Bb + (size_t)(rb + lrow) * K + k0 + lk, &sB[rb * 64]);
    }
    __syncthreads();
#pragma unroll
    for (int kk = 0; kk < 2; ++kk) {
      bf16x8 af[4], bfr[4];
#pragma unroll
      for (int mi = 0; mi < 4; ++mi)
        af[mi] = *(const bf16x8*)&sA[(wm * 64 + mi * 16 + l16) * 64 + kk * 32 + lhi * 8];
#pragma unroll
      for (int ni = 0; ni < 4; ++ni)
        bfr[ni] = *(const bf16x8*)&sB[(wn * 64 + ni * 16 + l16) * 64 + kk * 32 + lhi * 8];
#pragma unroll
      for (int mi = 0; mi < 4; ++mi)
#pragma unroll
        for (int ni = 0; ni < 4; ++ni)
          acc[mi][ni] = __builtin_amdgcn_mfma_f32_16x16x32_bf16(af[mi], bfr[ni], acc[mi][ni], 0, 0, 0);
    }
    __syncthreads();
  }

  unsigned short* outB = out2 + (size_t)z * Nn * Ff;
  const float* bias = b1_l + z * 4096;
#pragma unroll
  for (int mi = 0; mi < 4; ++mi) {
#pragma unroll
    for (int ni = 0; ni < 4; ++ni) {
#pragma unroll
      for (int j = 0; j < 4; ++j) {
        int r = brow * 128 + wm * 64 + mi * 16 + lhi * 4 + j;
        int c = bcol * 128 + wn * 64 + ni * 16 + l16;
        float v = acc[mi][ni][j] + bias[c];
        v = v > 0.f ? v : 0.f;
        outB[(size_t)r * Ncol + c] = f2bf(v);
      }
    }
  }
}

// ---------------- FFN2: t = f @ W2 + b2 + x1 (bf16 resid), bf16 out, BK=64, BN=64 ----------------
__global__ __launch_bounds__(256, 2) void ffn2_kernel(
    const unsigned short* __restrict__ A2, const unsigned short* __restrict__ Bt_l,
    unsigned short* __restrict__ out2, const float* __restrict__ b2_l,
    const unsigned short* __restrict__ resid2) {
  const int K = Ff, Ncol = 256;
  const size_t ZS = (size_t)Nn * Dm;
  __shared__ __align__(16) unsigned short sA[128 * 64];
  __shared__ __align__(16) unsigned short sB[64 * 64];
  int tid = threadIdx.x, wave = tid >> 6, lane = tid & 63;
  int l16 = lane & 15, lhi = lane >> 4;
  int brow = blockIdx.x, bcol = blockIdx.y, z = blockIdx.z;
  int wm = wave >> 1, wn = wave & 1;  // wave tile 64x32

  const unsigned short* Ab = A2 + (size_t)z * Nn * Ff + (size_t)brow * 128 * K;
  const unsigned short* Bb = Bt_l + (size_t)z * 4 * Ff * 256 + (size_t)bcol * 64 * K;
  int lrow = lane >> 3, lk = (lane & 7) * 8;

  f32x4 acc[4][2] = {};

  for (int k0 = 0; k0 < K; k0 += 64) {
#pragma unroll
    for (int r = 0; r < 4; ++r) {
      int rb = r * 32 + wave * 8;
      async_copy16(Ab + (size_t)(rb + lrow) * K + k0 + lk, &sA[rb * 64]);
      if (r < 2)
        async_copy16(Bb + (size_t)(rb + lrow) * K + k0 + lk, &sB[rb * 64]);
    }
    __syncthreads();
#pragma unroll
    for (int kk = 0; kk < 2; ++kk) {
      bf16x8 af[4], bfr[2];
#pragma unroll
      for (int mi = 0; mi < 4; ++mi)
        af[mi] = *(const bf16x8*)&sA[(wm * 64 + mi * 16 + l16) * 64 + kk * 32 + lhi * 8];
#pragma unroll
      for (int ni = 0; ni < 2; ++ni)
        bfr[ni] = *(const bf16x8*)&sB[(wn * 32 + ni * 16 + l16) * 64 + kk * 32 + lhi * 8];
#pragma unroll
      for (int mi = 0; mi < 4; ++mi)
#pragma unroll
        for (int ni = 0; ni < 2; ++ni)
          acc[mi][ni] = __builtin_amdgcn_mfma_f32_16x16x32_bf16(af[mi], bfr[ni], acc[mi][ni], 0, 0, 0);
    }
    __syncthreads();
  }

  unsigned short* outB = out2 + z * ZS;
  const float* bias = b2_l + z * 1024;
  const unsigned short* resid = resid2 + z * ZS;
#pragma unroll
  for (int mi = 0; mi < 4; ++mi) {
#pragma unroll
    for (int ni = 0; ni < 2; ++ni) {
#pragma unroll
      for (int j = 0; j < 4; ++j) {
        int r = brow * 128 + wm * 64 + mi * 16 + lhi * 4 + j;
        int c = bcol * 64 + wn * 32 + ni * 16 + l16;
        float v = acc[mi][ni][j] + bias[c] + bf2f(resid[(size_t)r * Ncol + c]);
        outB[(size_t)r * Ncol + c] = f2bf(v);
      }
    }
  }
}

// ---------------- wave-per-node fused softmax + aggregation + bias + residual + LN1 ----------------
// grid (Nn/4, 2): y = stream. 4 waves/block. Barrier-free. Residual read bf16; output bf16 only.
__global__ __launch_bounds__(256) void agg_kernel(
    const unsigned short* __restrict__ hbuf2, const float* __restrict__ a_s2,
    const float* __restrict__ a_d2,
    const int* __restrict__ rowptr, const int* __restrict__ csrc,
    const float* __restrict__ bias_l, const unsigned short* __restrict__ x01b,
    const float* __restrict__ g1_l, const float* __restrict__ bt1_l,
    unsigned short* __restrict__ x1b2) {
  __shared__ float sw[4][320];  // [wave][slot*5 + head]  (stride 5: conflict-free)
  __shared__ int ssrc[4][64];
  const size_t ZS = (size_t)Nn * Dm;
  int z = blockIdx.y;
  const unsigned short* hb = hbuf2 + z * ZS;
  const float* a_s = a_s2 + (size_t)z * Nn * 4;
  const float* a_d = a_d2 + (size_t)z * Nn * 4;
  const float* bias = bias_l + z * 1024;
  const unsigned short* xres = x01b + z * ZS;
  const float* g1 = g1_l + z * 1024;
  const float* bt1 = bt1_l + z * 1024;
  unsigned short* x1b = x1b2 + z * ZS;

  int wave = threadIdx.x >> 6, lane = threadIdx.x & 63;
  int n = blockIdx.x * 4 + wave;
  int l32 = lane & 31;
  int par = lane >> 5;         // edge parity
  int hch = l32 >> 3;          // head of my channel block
  int c0 = l32 * 8;            // my 8 channels
  int beg = rowptr[n], end = rowptr[n + 1];
  float4 adv = *(const float4*)&a_d[n * 4];
  const float NI = -__builtin_inff();
  float4 m4 = {NI, NI, NI, NI};
  float acc[8] = {};
  float den = 0.f;

  for (int base = beg; base < end; base += 64) {
    int cnt = min(64, end - base);
    // --- score phase: lane = edge slot ---
    float4 ev = {NI, NI, NI, NI};
    if (lane < cnt) {
      int s = csrc[base + lane];
      ssrc[wave][lane] = s;
      float4 as = *(const float4*)&a_s[s * 4];
      float e0 = as.x + adv.x; ev.x = e0 > 0.f ? e0 : 0.2f * e0;
      float e1 = as.y + adv.y; ev.y = e1 > 0.f ? e1 : 0.2f * e1;
      float e2 = as.z + adv.z; ev.z = e2 > 0.f ? e2 : 0.2f * e2;
      float e3 = as.w + adv.w; ev.w = e3 > 0.f ? e3 : 0.2f * e3;
    }
    // per-head chunk max across 64 lanes
    float4 mv = ev;
#pragma unroll
    for (int off = 32; off; off >>= 1) {
      mv.x = fmaxf(mv.x, __shfl_xor(mv.x, off));
      mv.y = fmaxf(mv.y, __shfl_xor(mv.y, off));
      mv.z = fmaxf(mv.z, __shfl_xor(mv.z, off));
      mv.w = fmaxf(mv.w, __shfl_xor(mv.w, off));
    }
    float4 m4n;
    m4n.x = fmaxf(m4.x, mv.x); m4n.y = fmaxf(m4.y, mv.y);
    m4n.z = fmaxf(m4.z, mv.z); m4n.w = fmaxf(m4.w, mv.w);
    // rescale my channels (first chunk: exp(-inf)=0)
    float rm = __expf(sel4(m4, hch) - sel4(m4n, hch));
#pragma unroll
    for (int j = 0; j < 8; ++j) acc[j] *= rm;
    den *= rm;
    // edge weights -> LDS
    if (lane < cnt) {
      float* swl = &sw[wave][lane * 5];
      swl[0] = __expf(ev.x - m4n.x);
      swl[1] = __expf(ev.y - m4n.y);
      swl[2] = __expf(ev.z - m4n.z);
      swl[3] = __expf(ev.w - m4n.w);
    }
    m4 = m4n;
    __builtin_amdgcn_wave_barrier();  // same-wave LDS ops are in-order; fence the compiler
    // --- PV phase: 2 edges per iteration ---
    for (int i = par; i < cnt; i += 2) {
      float w = sw[wave][i * 5 + hch];
      int s_i = ssrc[wave][i];
      bf16x8 hv = *(const bf16x8*)(hb + (size_t)s_i * 256 + c0);
#pragma unroll
      for (int j = 0; j < 8; ++j)
        acc[j] = fmaf(bf2f((unsigned short)hv[j]), w, acc[j]);
      den += w;
    }
    __builtin_amdgcn_wave_barrier();
  }

  // combine edge parities (lane ^ 32 holds same channels, other parity)
#pragma unroll
  for (int j = 0; j < 8; ++j) acc[j] += __shfl_xor(acc[j], 32);
  den += __shfl_xor(den, 32);

  float invden = 1.f / fmaxf(den, 1e-16f);
  bf16x8 rv = *(const bf16x8*)(xres + (size_t)n * 256 + c0);
  float outv[8];
  float s1 = 0.f, s2 = 0.f;
#pragma unroll
  for (int j = 0; j < 8; ++j) {
    float v = acc[j] * invden + bias[c0 + j] + bf2f((unsigned short)rv[j]);
    outv[j] = v;
    s1 += v;
    s2 += v * v;
  }
  // LN reduce over the 32-lane half (halves hold identical data)
#pragma unroll
  for (int off = 16; off; off >>= 1) {
    s1 += __shfl_xor(s1, off);
    s2 += __shfl_xor(s2, off);
  }
  float mean = s1 * (1.f / 256.f);
  float var = s2 * (1.f / 256.f) - mean * mean;
  float rst = rsqrtf(var + 1e-5f);
  if (par == 0) {
    unsigned short yb[8];
#pragma unroll
    for (int j = 0; j < 8; ++j)
      yb[j] = f2bf((outv[j] - mean) * rst * g1[c0 + j] + bt1[c0 + j]);
    *(bf16x8*)&x1b[(size_t)n * 256 + c0] = *(bf16x8*)yb;
  }
}

// ---------------- dual LN2 (wave per node) + optional next-layer prep ----------------
// reads bf16 tb2; writes f32 states + (PREP) bf16 next-layer inputs.
template <int PREP>
__global__ __launch_bounds__(256) void ln2_kernel(const unsigned short* __restrict__ tb2,
                                                  const float* __restrict__ g2_l,
                                                  const float* __restrict__ bt2_l,
                                                  float* __restrict__ out_hf,
                                                  float* __restrict__ out_hs,
                                                  unsigned short* __restrict__ x01b) {
  const size_t ZS = (size_t)Nn * Dm;
  int wave = threadIdx.x >> 6, lane = threadIdx.x & 63;
  int n = blockIdx.x * 4 + wave;
  int c0 = lane * 4;
  size_t idx = (size_t)n * 256 + c0;
  ushort4 u0 = *(const ushort4*)&tb2[idx];
  ushort4 u1 = *(const ushort4*)&tb2[ZS + idx];
  float v0[4] = {bf2f(u0.x), bf2f(u0.y), bf2f(u0.z), bf2f(u0.w)};
  float v1[4] = {bf2f(u1.x), bf2f(u1.y), bf2f(u1.z), bf2f(u1.w)};
  float a0 = 0.f, b0 = 0.f, a1 = 0.f, b1 = 0.f;
#pragma unroll
  for (int j = 0; j < 4; ++j) {
    a0 += v0[j]; b0 += v0[j] * v0[j];
    a1 += v1[j]; b1 += v1[j] * v1[j];
  }
#pragma unroll
  for (int off = 32; off; off >>= 1) {
    a0 += __shfl_xor(a0, off);
    b0 += __shfl_xor(b0, off);
    a1 += __shfl_xor(a1, off);
    b1 += __shfl_xor(b1, off);
  }
  float m0 = a0 * (1.f / 256.f), m1 = a1 * (1.f / 256.f);
  float r0 = rsqrtf(b0 * (1.f / 256.f) - m0 * m0 + 1e-5f);
  float r1 = rsqrtf(b1 * (1.f / 256.f) - m1 * m1 + 1e-5f);
  float4 y0, y1;
  unsigned short p0[4], p1[4];
#pragma unroll
  for (int j = 0; j < 4; ++j) {
    float yf = (v0[j] - m0) * r0 * g2_l[c0 + j] + bt2_l[c0 + j];
    float ys = (v1[j] - m1) * r1 * g2_l[1024 + c0 + j] + bt2_l[1024 + c0 + j];
    ((float*)&y0)[j] = yf;
    ((float*)&y1)[j] = ys;
    if (PREP) { p0[j] = f2bf(yf + ys); p1[j] = f2bf(ys); }
  }
  *(float4*)&out_hf[idx] = y0;
  *(float4*)&out_hs[idx] = y1;
  if (PREP) {
    *(ushort4*)&x01b[idx] = *(ushort4*)p0;
    *(ushort4*)&x01b[ZS + idx] = *(ushort4*)p1;
  }
}

extern "C" void kernel_launch(void* const* d_in, const int* in_sizes, int n_in,
                              void* d_out, int out_size, void* d_ws, size_t ws_size,
                              hipStream_t stream) {
  const float* hf_in = (const float*)d_in[0];
  const float* hs_in = (const float*)d_in[1];
  const int* ei = (const int*)d_in[2];
  const int E = in_sizes[2] / 2;
  const float* Wgat = (const float*)d_in[3];
  const float* att_src = (const float*)d_in[4];
  const float* att_dst = (const float*)d_in[5];
  const float* bias_gat = (const float*)d_in[6];
  const float* W1 = (const float*)d_in[7];
  const float* b1 = (const float*)d_in[8];
  const float* W2 = (const float*)d_in[9];
  const float* b2 = (const float*)d_in[10];
  const float* g1 = (const float*)d_in[11];
  const float* bt1 = (const float*)d_in[12];
  const float* g2 = (const float*)d_in[13];
  const float* bt2 = (const float*)d_in[14];
  const int* src = ei;
  const int* dst = ei + E;
  const size_t ZS = (size_t)Nn * Dm;

  // ---- carve workspace ----
  char* wsp = (char*)d_ws;
  size_t off = 0;
  auto carve = [&](size_t bytes) -> void* {
    void* p = wsp + off;
    off += (bytes + 255) & ~(size_t)255;
    return p;
  };
  unsigned short* Wgt  = (unsigned short*)carve((size_t)8 * 256 * 256 * 2);
  unsigned short* W1t  = (unsigned short*)carve((size_t)8 * 256 * 1024 * 2);
  unsigned short* W2t  = (unsigned short*)carve((size_t)8 * 1024 * 256 * 2);
  int* cnt      = (int*)carve((size_t)Nn * 4);
  int* rowptr   = (int*)carve((size_t)(Nn + 1) * 4);
  int* cursor   = (int*)carve((size_t)Nn * 4);
  int* part     = (int*)carve((size_t)Nn * 4);
  int* bsum     = (int*)carve((size_t)64 * 4);
  int* bbase    = (int*)carve((size_t)64 * 4);
  int* csrc     = (int*)carve((size_t)E * 4);
  unsigned short* x01b = (unsigned short*)carve(2 * ZS * 2);  // [z]: layer input bf16
  unsigned short* hbuf2 = (unsigned short*)carve(2 * ZS * 2); // [z]: proj out bf16
  float* a_s2   = (float*)carve((size_t)2 * Nn * 4 * 4);
  float* a_d2   = (float*)carve((size_t)2 * Nn * 4 * 4);
  unsigned short* x1b2 = (unsigned short*)carve(2 * ZS * 2);  // [z]: LN1 out bf16
  unsigned short* tb2  = (unsigned short*)carve(2 * ZS * 2);  // [z]: FFN2 out (pre-LN2) bf16
  unsigned short* f_b2 = (unsigned short*)carve((size_t)2 * Nn * Ff * 2);  // [z]: FFN1 out
  if (off > ws_size) return;  // workspace too small — fail visibly

  // ---- once per call: weights (tiled transpose) + CSR ----
  wconvt_kernel<<<dim3(4, 4, 8), 256, 0, stream>>>(Wgat, Wgt, 256, 256);
  wconvt_kernel<<<dim3(16, 4, 8), 256, 0, stream>>>(W1, W1t, 256, 1024);
  wconvt_kernel<<<dim3(4, 16, 8), 256, 0, stream>>>(W2, W2t, 1024, 256);
  hipMemsetAsync(cnt, 0, (size_t)Nn * 4, stream);
  count_kernel<<<1024, 256, 0, stream>>>(dst, E, cnt);
  scan1_kernel<<<64, 256, 0, stream>>>(cnt, part, bsum);
  scan2_kernel<<<1, 64, 0, stream>>>(bsum, bbase, rowptr);
  scan3_kernel<<<64, 256, 0, stream>>>(part, bbase, rowptr, cursor);
  fill_kernel<<<1024, 256, 0, stream>>>(src, dst, E, cursor, csrc);

  float* out_hf = (float*)d_out;
  float* out_hs = out_hf + ZS;

  prep_kernel<<<2048, 256, 0, stream>>>(hf_in, hs_in, x01b, Nn * Dm);

  for (int l = 0; l < 4; ++l) {
    // proj (both streams) + fused scores
    proj_kernel<<<dim3(128, 4, 2), 256, 0, stream>>>(
        x01b, Wgt + (size_t)l * 65536, hbuf2,
        att_src + l * 256, att_dst + l * 256, a_s2, a_d2);
    // segment softmax + aggregate + bias + residual + LN1 (both streams)
    agg_kernel<<<dim3(Nn / 4, 2), 256, 0, stream>>>(
        hbuf2, a_s2, a_d2, rowptr, csrc,
        bias_gat + l * 256, x01b, g1 + l * 256, bt1 + l * 256, x1b2);
    // FFN (both streams per dispatch)
    ffn1_kernel<<<dim3(128, 8, 2), 256, 0, stream>>>(
        x1b2, W1t + (size_t)l * 256 * 1024, f_b2, b1 + l * 1024);
    ffn2_kernel<<<dim3(128, 4, 2), 256, 0, stream>>>(
        f_b2, W2t + (size_t)l * 1024 * 256, tb2, b2 + l * 256, x1b2);
    // dual LN2 -> states (+ next-layer prep for l<3)
    if (l < 3) {
      ln2_kernel<1><<<Nn / 4, 256, 0, stream>>>(tb2, g2 + l * 256, bt2 + l * 256,
                                                out_hf, out_hs, x01b);
    } else {
      ln2_kernel<0><<<Nn / 4, 256, 0, stream>>>(tb2, g2 + l * 256, bt2 + l * 256,
                                                out_hf, out_hs, x01b);
    }
  }
}